// Round 1
// baseline (604.710 us; speedup 1.0000x reference)
//
#include <hip/hip_runtime.h>
#include <hip/hip_bf16.h>
#include <stdint.h>

// EmotionTriadFusion on MI355X — Round 6: 256x256 deep-pipelined GEMM for the
// three big N=1024 GEMMs + coalesced prep (tiled transposes, MFMA weight folds).
// B=16384, F=1024, E=28, A=2, T=128, H=4, HD=32. fp32 I/O, bf16 MFMA internals.
//
// R5 was 557 us. G5 counters: MfmaUtil 28%, VALUBusy 50%, HBM 14% -> the 128^2
// tile is LDS-read bound (8 ds_read_b128 ~96cyc vs 16 MFMA ~78cyc per kk) and
// drains vmcnt(0) at every barrier. gemm256: 256^2 tile, 8 waves (128x64/wave
// -> MFMA pipe >= LDS pipe), 2x64KB LDS double buffer, distance-2 prefetch
// with counted s_waitcnt vmcnt(8) + raw s_barrier (no compiler drain),
// setprio(1) around MFMA clusters. Schedule safety: stage(t+2)->buf[t&1] only
// after lgkmcnt(0)-drain + barrier of all tile-t reads; vmcnt(8) at iter end
// guarantees tile t+1 landed before the closing barrier.
// prep: old scalar folds/transposes (stride-4KB loads) -> LDS-tiled
// transpose_cvt + two tiny bf16 gemm128 folds (WQQT, WOCT).
//
// Pipeline:
//  ffb_convert: ff fp32 -> FFB bf16 (ws)
//  prep_small : WKVT/BKV/BQQ/BOC + bf16 converts of Wq_in, Wo
//  transpose_cvt x5: WQT, WCT, WST, WG1T, WG2T (coalesced, LDS 32x33)
//  fold GEMMs : WQQT = WQT @ WQINB^T ; WOCT = WCT @ WOB^T   (gemm128, no bias)
//  tokens  : softmax(28)->LN->(28->128)matmul->GELU x2 + affect -> TOK bf16
//  G1 qh   = FFB @ WqqT           M=16384 K=1024 N=128   -> QH bf16 (MT=64)
//  G2 kvh  = TOK @ [Wk|Wv]T       M=49152 K=128  N=256   -> summary slot
//  attn    -> attw fp32 (d_out) + APRE bf16 (ws)
//  G3 ctx  = APRE @ WocT          M=16384 K=128  N=1024  -> refined slot (bf16)
//  G5 gh   = gelu([FFB|CTX]@Wg1T) M=16384 K=2048 N=1024  -> summary (gemm256)
//  G6 pre  = FFB + sigmoid(gh@Wg2T)*ctx -> PRE bf16      (gemm256, aliases FFB)
//  G4 summ = gelu(TOK @ WsT)      M=16384 K=384  N=1024  -> summary f32 (gemm256)
//  ln      : LayerNorm(1024) PRE bf16 -> refined fp32 (final)
//
// ws peak = 62,199,296 B (~59.3 MB); prep temporaries live in the (then-dead)
// QH slot and are overwritten by G1's output afterwards.

using bf16 = __hip_bfloat16;
typedef __bf16 bf16x8 __attribute__((ext_vector_type(8)));
typedef float f32x4 __attribute__((ext_vector_type(4)));

__device__ __forceinline__ float b2f(bf16 x) { return __bfloat162float(x); }
__device__ __forceinline__ bf16 f2b(float x) { return __float2bfloat16(x); }

// tanh via hw exp; guards overflow (z>=0 -> t<=1, no NaN).
__device__ __forceinline__ float fast_tanh(float y) {
  float z = fabsf(y);
  float t = __expf(-2.f * z);
  float r = (1.f - t) / (1.f + t);
  return copysignf(r, y);
}
// tanh-form GELU: |err vs erf-GELU| <~ 3e-3, within 0.11 threshold budget.
__device__ __forceinline__ float gelu_f(float x) {
  return 0.5f * x * (1.f + fast_tanh(0.7978845608028654f * (x + 0.044715f * x * x * x)));
}
__device__ __forceinline__ float sigmoid_f(float v) {
  return 1.f / (1.f + __expf(-v));  // __expf(+big)=inf -> 1/inf=0, no NaN
}

__device__ __forceinline__ void async_ld16(const void* g, void* l) {
  using GP = const __attribute__((address_space(1))) uint32_t*;
  using LP = __attribute__((address_space(3))) uint32_t*;
  __builtin_amdgcn_global_load_lds((GP)g, (LP)l, 16, 0, 0);
}

// ---------------------------------------------------------------------------
// ff fp32 -> bf16, 4 elems/thread.
// ---------------------------------------------------------------------------
__global__ void ffb_convert(const float* __restrict__ src, bf16* __restrict__ dst) {
  size_t i = ((size_t)blockIdx.x * 256 + threadIdx.x) * 4;
  float4 v = *reinterpret_cast<const float4*>(src + i);
  ushort4 o;
  o.x = __builtin_bit_cast(unsigned short, f2b(v.x));
  o.y = __builtin_bit_cast(unsigned short, f2b(v.y));
  o.z = __builtin_bit_cast(unsigned short, f2b(v.z));
  o.w = __builtin_bit_cast(unsigned short, f2b(v.w));
  *reinterpret_cast<ushort4*>(dst + i) = o;
}

// ---------------------------------------------------------------------------
// Tiled MFMA GEMM (128-wide N tiles): C = act(A @ BT^T + bias).
// Tile MTx128 (MT=128 or 64), BK=64, 4 waves 2x2, wave (MT/2)x64.
// Used for small/odd-shape GEMMs (G1,G2,G3) and the two weight folds.
// ---------------------------------------------------------------------------
template <int EPI, typename OutT, int MT>
__launch_bounds__(256)
__global__ void gemm128(const bf16* A0, const bf16* A1, int ksplit, int lda0, int lda1,
                        const bf16* __restrict__ BT, int K,
                        const float* __restrict__ bias,
                        OutT* out, int ldo,
                        const bf16* ffp, const bf16* ctxp, int ldfc)
{
  constexpr int MIC = MT / 32;
  __shared__ uint16_t smA[MT * 64];
  __shared__ uint16_t smB[128 * 64];
  const int tid = threadIdx.x;
  const int w = tid >> 6;
  const int l = tid & 63;
  const int m0 = blockIdx.x * MT;
  const int n0 = blockIdx.y * 128;
  const int wr = w >> 1, wc = w & 1;
  const int lrow = l & 15, lquad = l >> 4;
  const int rb = w * 8 + (l >> 3);
  const int cpos = l & 7;

  const f32x4 vzero = {0.f, 0.f, 0.f, 0.f};
  f32x4 acc[MIC][4];
#pragma unroll
  for (int i = 0; i < MIC; i++)
#pragma unroll
    for (int j = 0; j < 4; j++) acc[i][j] = vzero;

  for (int k0 = 0; k0 < K; k0 += 64) {
    __syncthreads();
#pragma unroll
    for (int i = 0; i < MIC; i++) {
      int row = i * 32 + rb;
      int cg = cpos ^ (row & 7);
      int kcol = k0 + cg * 8;
      const bf16* gp = (kcol < ksplit)
                           ? (A0 + (size_t)(m0 + row) * lda0 + kcol)
                           : (A1 + (size_t)(m0 + row) * lda1 + (kcol - ksplit));
      async_ld16(gp, &smA[(i * 32 + w * 8) * 64]);
    }
#pragma unroll
    for (int i = 0; i < 4; i++) {
      int row = i * 32 + rb;
      int cg = cpos ^ (row & 7);
      const bf16* gq = BT + (size_t)(n0 + row) * K + k0 + cg * 8;
      async_ld16(gq, &smB[(i * 32 + w * 8) * 64]);
    }
    __syncthreads();
#pragma unroll
    for (int kk = 0; kk < 2; kk++) {
      bf16x8 af[MIC], bfr[4];
      const int cc = kk * 4 + lquad;
#pragma unroll
      for (int mi = 0; mi < MIC; mi++) {
        int r = wr * (MT / 2) + mi * 16 + lrow;
        af[mi] = *(const bf16x8*)&smA[r * 64 + ((cc ^ (r & 7)) << 3)];
      }
#pragma unroll
      for (int ni = 0; ni < 4; ni++) {
        int r = wc * 64 + ni * 16 + lrow;
        bfr[ni] = *(const bf16x8*)&smB[r * 64 + ((cc ^ (r & 7)) << 3)];
      }
#pragma unroll
      for (int mi = 0; mi < MIC; mi++)
#pragma unroll
        for (int ni = 0; ni < 4; ni++)
          acc[mi][ni] =
              __builtin_amdgcn_mfma_f32_16x16x32_bf16(af[mi], bfr[ni], acc[mi][ni], 0, 0, 0);
    }
  }

  // epilogue: C/D layout col=lane&15, row=(lane>>4)*4+reg
#pragma unroll
  for (int mi = 0; mi < MIC; mi++) {
#pragma unroll
    for (int ni = 0; ni < 4; ni++) {
#pragma unroll
      for (int r = 0; r < 4; r++) {
        int row = m0 + wr * (MT / 2) + mi * 16 + lquad * 4 + r;
        int col = n0 + wc * 64 + ni * 16 + lrow;
        float v = acc[mi][ni][r] + (bias ? bias[col] : 0.f);
        if (EPI == 1) v = gelu_f(v);
        if (EPI == 2) {
          float gate = sigmoid_f(v);
          size_t fo = (size_t)row * ldfc + col;
          v = b2f(ffp[fo]) + gate * b2f(ctxp[fo]);
        }
        if constexpr (__is_same(OutT, float))
          out[(size_t)row * ldo + col] = v;
        else
          out[(size_t)row * ldo + col] = f2b(v);
      }
    }
  }
}

// ---------------------------------------------------------------------------
// gemm256: 256x256 tile, BK=64, 512 thr = 8 waves (2Mx4N), wave = 128x64.
// Double-buffered LDS (2 x 64KB), distance-2 prefetch, counted vmcnt(8),
// raw s_barrier (no vmcnt drain), setprio around MFMA clusters.
// Per iteration t: read kk0 -> MFMA ; read kk1 -> lgkmcnt(0) -> barrier
// (all waves done with buf[t&1]) -> stage tile t+2 into buf[t&1] -> MFMA kk1
// -> vmcnt(8) (tile t+1 landed) -> barrier.
// ---------------------------------------------------------------------------
template <int EPI, typename OutT>
__launch_bounds__(512, 2)
__global__ void gemm256(const bf16* A0, const bf16* A1, int ksplit, int lda0, int lda1,
                        const bf16* __restrict__ BT, int K,
                        const float* __restrict__ bias,
                        OutT* out, int ldo,
                        const bf16* ffp, const bf16* ctxp, int ldfc)
{
  __shared__ uint16_t smA[2][256 * 64];
  __shared__ uint16_t smB[2][256 * 64];
  const int tid = threadIdx.x;
  const int w = tid >> 6;       // wave 0..7
  const int l = tid & 63;
  const int m0 = blockIdx.x * 256;
  const int n0 = blockIdx.y * 256;
  const int wr = w >> 2;        // M-half 0..1
  const int wc = w & 3;         // N-quarter 0..3
  const int lrow = l & 15, lquad = l >> 4;
  const int rb = tid >> 3;      // staging row within 64-row group
  const int cpos = tid & 7;     // staging 16B-chunk position
  const int NT = K >> 6;

  const f32x4 vzero = {0.f, 0.f, 0.f, 0.f};
  f32x4 acc[8][4];
#pragma unroll
  for (int mi = 0; mi < 8; mi++)
#pragma unroll
    for (int ni = 0; ni < 4; ni++) acc[mi][ni] = vzero;

  // stage K-tile tt into buffer buf: 4+4 global_load_lds of 16B/lane.
  // LDS (row, c) holds global chunk c ^ (row&7); dest is wave-uniform base
  // + lane*16 (global_load_lds constraint), rows w*8..w*8+7 per wave.
  auto stage = [&](int buf, int tt) {
    const int k0 = tt << 6;
    const bf16* Ab; int la, kc;
    if (k0 < ksplit) { Ab = A0; la = lda0; kc = k0; }
    else             { Ab = A1; la = lda1; kc = k0 - ksplit; }
#pragma unroll
    for (int i = 0; i < 4; i++) {
      const int row = i * 64 + rb;
      const int cg = cpos ^ (row & 7);
      async_ld16(Ab + (size_t)(m0 + row) * la + kc + cg * 8,
                 &smA[buf][(i * 64 + w * 8) * 64]);
    }
#pragma unroll
    for (int i = 0; i < 4; i++) {
      const int row = i * 64 + rb;
      const int cg = cpos ^ (row & 7);
      async_ld16(BT + (size_t)(n0 + row) * K + k0 + cg * 8,
                 &smB[buf][(i * 64 + w * 8) * 64]);
    }
  };

  int cur = 0;

  auto readfrags = [&](int kk, bf16x8 (&af)[8], bf16x8 (&bfr)[4]) {
    const int cc = kk * 4 + lquad;
#pragma unroll
    for (int mi = 0; mi < 8; mi++) {
      int r = wr * 128 + mi * 16 + lrow;
      af[mi] = *(const bf16x8*)&smA[cur][r * 64 + (((cc) ^ (r & 7)) << 3)];
    }
#pragma unroll
    for (int ni = 0; ni < 4; ni++) {
      int r = wc * 64 + ni * 16 + lrow;
      bfr[ni] = *(const bf16x8*)&smB[cur][r * 64 + (((cc) ^ (r & 7)) << 3)];
    }
  };
  auto domfma = [&](bf16x8 (&af)[8], bf16x8 (&bfr)[4]) {
#pragma unroll
    for (int mi = 0; mi < 8; mi++)
#pragma unroll
      for (int ni = 0; ni < 4; ni++)
        acc[mi][ni] =
            __builtin_amdgcn_mfma_f32_16x16x32_bf16(af[mi], bfr[ni], acc[mi][ni], 0, 0, 0);
  };

  // prologue: stage tiles 0,1; wait tile 0 (8 oldest loads), sync.
  stage(0, 0);
  stage(1, 1);
  asm volatile("s_waitcnt vmcnt(8)" ::: "memory");
  __builtin_amdgcn_s_barrier();
  __builtin_amdgcn_sched_barrier(0);

  for (int t = 0; t < NT; ++t) {
    bf16x8 af[8], bfr[4];
    readfrags(0, af, bfr);
    __builtin_amdgcn_s_setprio(1);
    domfma(af, bfr);
    __builtin_amdgcn_s_setprio(0);
    readfrags(1, af, bfr);
    asm volatile("s_waitcnt lgkmcnt(0)" ::: "memory");  // all buf[cur] reads done
    __builtin_amdgcn_s_barrier();                       // ...for every wave
    __builtin_amdgcn_sched_barrier(0);
    if (t + 2 < NT) stage(cur, t + 2);                  // safe: buf[cur] free
    __builtin_amdgcn_s_setprio(1);
    domfma(af, bfr);
    __builtin_amdgcn_s_setprio(0);
    if (t + 2 < NT) {
      asm volatile("s_waitcnt vmcnt(8)" ::: "memory");  // tile t+1 landed
    } else {
      asm volatile("s_waitcnt vmcnt(0)" ::: "memory");  // tail: drain
    }
    __builtin_amdgcn_s_barrier();
    __builtin_amdgcn_sched_barrier(0);
    cur ^= 1;
  }

  // epilogue: C/D layout col=lane&15, row=(lane>>4)*4+reg
#pragma unroll
  for (int mi = 0; mi < 8; mi++) {
#pragma unroll
    for (int ni = 0; ni < 4; ni++) {
#pragma unroll
      for (int r = 0; r < 4; r++) {
        int row = m0 + wr * 128 + mi * 16 + lquad * 4 + r;
        int col = n0 + wc * 64 + ni * 16 + lrow;
        float v = acc[mi][ni][r] + (bias ? bias[col] : 0.f);
        if (EPI == 1) v = gelu_f(v);
        if (EPI == 2) {
          float gate = sigmoid_f(v);
          size_t fo = (size_t)row * ldfc + col;
          v = b2f(ffp[fo]) + gate * b2f(ctxp[fo]);
        }
        if constexpr (__is_same(OutT, float))
          out[(size_t)row * ldo + col] = v;
        else
          out[(size_t)row * ldo + col] = f2b(v);
      }
    }
  }
}

// ---------------------------------------------------------------------------
// Coalesced transpose + fp32->bf16 convert: out[c][r] = in[r][c].
// Block 256 thr handles a 32x32 tile; LDS 32x33 (conflict-free).
// Grid: (C/32, R/32); R,C multiples of 32.
// ---------------------------------------------------------------------------
__global__ void transpose_cvt(const float* __restrict__ in, bf16* __restrict__ out,
                              int R, int C)
{
  __shared__ float tile[32][33];
  const int tx = threadIdx.x & 31, ty = threadIdx.x >> 5;  // ty in [0,8)
  const int c0 = blockIdx.x * 32, r0 = blockIdx.y * 32;
#pragma unroll
  for (int i = 0; i < 4; i++) {
    int r = ty + i * 8;
    tile[r][tx] = in[(size_t)(r0 + r) * C + c0 + tx];
  }
  __syncthreads();
#pragma unroll
  for (int i = 0; i < 4; i++) {
    int c = ty + i * 8;
    out[(size_t)(c0 + c) * R + r0 + tx] = f2b(tile[tx][c]);
  }
}

// ---------------------------------------------------------------------------
// Small prep: KV weight concat/transpose, folded biases, bf16 converts.
// All accesses coalesced or tiny. 181,632 threads total.
// ---------------------------------------------------------------------------
__global__ void prep_small(
    const float* __restrict__ Wk, const float* __restrict__ bk,
    const float* __restrict__ Wv, const float* __restrict__ bv,
    const float* __restrict__ Wq_in, const float* __restrict__ bq_in,
    const float* __restrict__ Wq, const float* __restrict__ bq,
    const float* __restrict__ Wo, const float* __restrict__ bo,
    const float* __restrict__ Wc, const float* __restrict__ bc,
    bf16* WKVT, float* BKV, float* BQQ, float* BOC, bf16* WQINB, bf16* WOB)
{
  int idx = blockIdx.x * 256 + threadIdx.x;
  if (idx < 32768) {  // WKVT[n][k] = (n<128 ? Wk : Wv)[k][n%128]
    int n = idx >> 7, k = idx & 127;
    WKVT[idx] = f2b((n < 128) ? Wk[k * 128 + n] : Wv[k * 128 + (n - 128)]);
    return;
  }
  idx -= 32768;
  if (idx < 256) { BKV[idx] = (idx < 128) ? bk[idx] : bv[idx - 128]; return; }
  idx -= 256;
  if (idx < 128) {  // BQQ[t] = bq_in @ Wq[:,t] + bq[t]   (coalesced over t)
    float s = bq[idx];
    for (int u = 0; u < 128; u++) s += bq_in[u] * Wq[u * 128 + idx];
    BQQ[idx] = s;
    return;
  }
  idx -= 128;
  if (idx < 1024) {  // BOC[f] = bo @ Wc[:,f] + bc[f]     (coalesced over f)
    float s = bc[idx];
    for (int t = 0; t < 128; t++) s += bo[t] * Wc[t * 1024 + idx];
    BOC[idx] = s;
    return;
  }
  idx -= 1024;
  if (idx < 131072) { WQINB[idx] = f2b(Wq_in[idx]); return; }  // [f][u] direct
  idx -= 131072;
  if (idx < 16384) { WOB[idx] = f2b(Wo[idx]); return; }        // [d][t] direct
}

// ---------------------------------------------------------------------------
// Tokens: fp32 in, bf16 TOK out. One block (128 thr) per row.
// ---------------------------------------------------------------------------
__device__ __forceinline__ void emb28(const float* __restrict__ logits,
                                      const float* __restrict__ g,
                                      const float* __restrict__ bb,
                                      const float* __restrict__ W,
                                      const float* __restrict__ wb,
                                      bf16* __restrict__ out, int t,
                                      float* sv, float* sp)
{
  if (t < 28) sv[t] = logits[t];
  __syncthreads();
  float mx = sv[0];
#pragma unroll
  for (int e = 1; e < 28; e++) mx = fmaxf(mx, sv[e]);
  if (t < 28) sp[t] = __expf(sv[t] - mx);
  __syncthreads();
  float sum = 0.f;
#pragma unroll
  for (int e = 0; e < 28; e++) sum += sp[e];
  float inv = 1.f / sum;
  float sp2 = 0.f;
#pragma unroll
  for (int e = 0; e < 28; e++) { float p = sp[e] * inv; sp2 += p * p; }
  const float mean = 1.f / 28.f;
  float var = sp2 * (1.f / 28.f) - mean * mean;
  float rstd = rsqrtf(var + 1e-5f);
  __syncthreads();
  if (t < 28) sp[t] = (sp[t] * inv - mean) * rstd * g[t] + bb[t];
  __syncthreads();
  float acc = wb[t];
#pragma unroll
  for (int e = 0; e < 28; e++) acc += sp[e] * W[e * 128 + t];
  out[t] = f2b(gelu_f(acc));
  __syncthreads();
}

__global__ void tokens_kernel(
    const float* __restrict__ exl, const float* __restrict__ iml, const float* __restrict__ affv,
    const float* __restrict__ geg, const float* __restrict__ geb,
    const float* __restrict__ Wex, const float* __restrict__ bex,
    const float* __restrict__ gig, const float* __restrict__ gib,
    const float* __restrict__ Wim, const float* __restrict__ bim,
    const float* __restrict__ gag, const float* __restrict__ gab,
    const float* __restrict__ Waf, const float* __restrict__ baf,
    bf16* __restrict__ tokens)
{
  __shared__ float sv[28], sp[28];
  const int b = blockIdx.x, t = threadIdx.x;
  bf16* trow = tokens + (size_t)b * 384;
  emb28(exl + (size_t)b * 28, geg, geb, Wex, bex, trow, t, sv, sp);
  emb28(iml + (size_t)b * 28, gig, gib, Wim, bim, trow + 128, t, sv, sp);
  float a0 = affv[(size_t)b * 2 + 0];
  float a1 = affv[(size_t)b * 2 + 1];
  float m = 0.5f * (a0 + a1);
  float d0 = a0 - m, d1 = a1 - m;
  float var = 0.5f * (d0 * d0 + d1 * d1);
  float rstd = rsqrtf(var + 1e-5f);
  float l0 = d0 * rstd * gag[0] + gab[0];
  float l1 = d1 * rstd * gag[1] + gab[1];
  float acc = baf[t] + l0 * Waf[t] + l1 * Waf[128 + t];
  trow[256 + t] = f2b(gelu_f(acc));
}

// ---------------------------------------------------------------------------
// Attention: per row, 4 heads x 3 keys; head = t/32, dim = t%32.
// ---------------------------------------------------------------------------
__global__ void attn_kernel(const bf16* __restrict__ qh, const bf16* __restrict__ kvh,
                            bf16* __restrict__ apre, float* __restrict__ attw)
{
  const int b = blockIdx.x, t = threadIdx.x;  // 128 threads
  float q = b2f(qh[(size_t)b * 128 + t]);
  const bf16* kv = kvh + (size_t)b * 3 * 256;
  float s[3], v[3];
#pragma unroll
  for (int i = 0; i < 3; i++) {
    float k = b2f(kv[i * 256 + t]);
    v[i] = b2f(kv[i * 256 + 128 + t]);
    float r = q * k;
#pragma unroll
    for (int off = 16; off > 0; off >>= 1) r += __shfl_down(r, off, 32);
    r = __shfl(r, 0, 32);
    s[i] = r * 0.17677669529663687f;  // 1/sqrt(32)
  }
  float mx = fmaxf(s[0], fmaxf(s[1], s[2]));
  float e0 = __expf(s[0] - mx), e1 = __expf(s[1] - mx), e2 = __expf(s[2] - mx);
  float inv = 1.f / (e0 + e1 + e2);
  float w0 = e0 * inv, w1 = e1 * inv, w2 = e2 * inv;
  apre[(size_t)b * 128 + t] = f2b(w0 * v[0] + w1 * v[1] + w2 * v[2]);
  __shared__ float aw[4][3];
  if ((t & 31) == 0) { int h = t >> 5; aw[h][0] = w0; aw[h][1] = w1; aw[h][2] = w2; }
  __syncthreads();
  if (t < 3)
    attw[(size_t)b * 3 + t] = 0.25f * (aw[0][t] + aw[1][t] + aw[2][t] + aw[3][t]);
}

// ---------------------------------------------------------------------------
// Output LayerNorm over 1024: bf16 in (PRE), fp32 out. One block/row.
// ---------------------------------------------------------------------------
__global__ void ln_out_kernel(const bf16* __restrict__ x, const float* __restrict__ g,
                              const float* __restrict__ bb, float* __restrict__ out)
{
  const int row = blockIdx.x, t = threadIdx.x;
  const bf16* xr = x + (size_t)row * 1024;
  ushort4 u = *reinterpret_cast<const ushort4*>(xr + t * 4);
  float v0 = __uint_as_float((uint32_t)u.x << 16);
  float v1 = __uint_as_float((uint32_t)u.y << 16);
  float v2 = __uint_as_float((uint32_t)u.z << 16);
  float v3 = __uint_as_float((uint32_t)u.w << 16);
  float s = v0 + v1 + v2 + v3;
  float s2 = v0 * v0 + v1 * v1 + v2 * v2 + v3 * v3;
#pragma unroll
  for (int off = 32; off > 0; off >>= 1) {
    s += __shfl_down(s, off, 64);
    s2 += __shfl_down(s2, off, 64);
  }
  __shared__ float ls[4], ls2[4];
  const int w = t >> 6;
  if ((t & 63) == 0) { ls[w] = s; ls2[w] = s2; }
  __syncthreads();
  float S = ls[0] + ls[1] + ls[2] + ls[3];
  float S2 = ls2[0] + ls2[1] + ls2[2] + ls2[3];
  float mean = S * (1.f / 1024.f);
  float var = S2 * (1.f / 1024.f) - mean * mean;
  float rstd = rsqrtf(var + 1e-5f);
  const int c = t * 4;
  float4 o;
  o.x = (v0 - mean) * rstd * g[c + 0] + bb[c + 0];
  o.y = (v1 - mean) * rstd * g[c + 1] + bb[c + 1];
  o.z = (v2 - mean) * rstd * g[c + 2] + bb[c + 2];
  o.w = (v3 - mean) * rstd * g[c + 3] + bb[c + 3];
  *reinterpret_cast<float4*>(out + (size_t)row * 1024 + c) = o;
}

// ---------------------------------------------------------------------------
extern "C" void kernel_launch(void* const* d_in, const int* in_sizes, int n_in,
                              void* d_out, int out_size, void* d_ws, size_t ws_size,
                              hipStream_t stream)
{
  const float* ff   = (const float*)d_in[0];
  const float* exl  = (const float*)d_in[1];
  const float* iml  = (const float*)d_in[2];
  const float* affv = (const float*)d_in[3];
  const float* geg = (const float*)d_in[4],  *geb = (const float*)d_in[5];
  const float* Wex = (const float*)d_in[6],  *bex = (const float*)d_in[7];
  const float* gig = (const float*)d_in[8],  *gib = (const float*)d_in[9];
  const float* Wim = (const float*)d_in[10], *bim = (const float*)d_in[11];
  const float* gag = (const float*)d_in[12], *gab = (const float*)d_in[13];
  const float* Waf = (const float*)d_in[14], *baf = (const float*)d_in[15];
  const float* Wq_in = (const float*)d_in[16], *bq_in = (const float*)d_in[17];
  const float* Wq = (const float*)d_in[18], *bq = (const float*)d_in[19];
  const float* Wk = (const float*)d_in[20], *bk = (const float*)d_in[21];
  const float* Wv = (const float*)d_in[22], *bv = (const float*)d_in[23];
  const float* Wo = (const float*)d_in[24], *bo = (const float*)d_in[25];
  const float* Wc = (const float*)d_in[26], *bc = (const float*)d_in[27];
  const float* Ws = (const float*)d_in[28], *bs = (const float*)d_in[29];
  const float* Wg1 = (const float*)d_in[30], *bg1 = (const float*)d_in[31];
  const float* Wg2 = (const float*)d_in[32], *bg2 = (const float*)d_in[33];
  const float* lng = (const float*)d_in[34], *lnb = (const float*)d_in[35];

  // workspace layout (bytes); peak = 62,199,296 (~59.3 MB)
  char* ws = (char*)d_ws;
  bf16*  WKVT = (bf16*)(ws + 0);         //  32768 el bf16
  float* BKV  = (float*)(ws + 65536);    //    256 el f32
  bf16*  WQQT = (bf16*)(ws + 66560);     // 131072 el bf16
  float* BQQ  = (float*)(ws + 328704);   //    128 el f32
  bf16*  WOCT = (bf16*)(ws + 329216);    // 131072 el bf16
  float* BOC  = (float*)(ws + 591360);   //   1024 el f32
  bf16*  WST  = (bf16*)(ws + 595456);    // 393216 el bf16
  bf16*  WG1T = (bf16*)(ws + 1381888);   // 2097152 el bf16
  bf16*  WG2T = (bf16*)(ws + 5576192);   // 1048576 el bf16
  bf16*  FFB  = (bf16*)(ws + 7673344);   // B*1024 (live: convert..G6)
  bf16*  PRE  = (bf16*)(ws + 7673344);   // B*1024, aliases FFB elem-wise (G6..ln)
  bf16*  TOK  = (bf16*)(ws + 41227776);  // B*384  (live: tokens..G4)
  bf16*  QH   = (bf16*)(ws + 53810688);  // B*128  (live: G1..attn)
  bf16*  APRE = (bf16*)(ws + 58004992);  // B*128  (live: attn..G3)

  // prep temporaries carved from the (not-yet-live) QH slot (4 MB avail):
  bf16* WQT   = (bf16*)(ws + 53810688);            //  16384 el (Wq^T)
  bf16* WOB   = (bf16*)(ws + 53810688 + 32768);    //  16384 el (Wo bf16)
  bf16* WQINB = (bf16*)(ws + 53810688 + 65536);    // 131072 el (Wq_in bf16)
  bf16* WCT   = (bf16*)(ws + 53810688 + 327680);   // 131072 el (Wc^T)

  float* outp = (float*)d_out;
  float* out_refined = outp;             // B*1024 f32; hosts CTX bf16 G3..G6
  float* out_attw    = outp + 16777216;  // B*3 f32
  float* out_summary = outp + 16826368;  // B*1024 f32; hosts KVH bf16 G2..attn, GATEH bf16 G5..G6
  bf16* CTX   = (bf16*)out_refined;
  bf16* KVH   = (bf16*)out_summary;
  bf16* GATEH = (bf16*)out_summary;

  ffb_convert<<<16384, 256, 0, stream>>>(ff, FFB);
  prep_small<<<710, 256, 0, stream>>>(Wk, bk, Wv, bv, Wq_in, bq_in, Wq, bq,
                                      Wo, bo, Wc, bc, WKVT, BKV, BQQ, BOC, WQINB, WOB);
  transpose_cvt<<<dim3(4, 4),   256, 0, stream>>>(Wq,  WQT,  128, 128);
  transpose_cvt<<<dim3(32, 4),  256, 0, stream>>>(Wc,  WCT,  128, 1024);
  transpose_cvt<<<dim3(32, 12), 256, 0, stream>>>(Ws,  WST,  384, 1024);
  transpose_cvt<<<dim3(32, 64), 256, 0, stream>>>(Wg1, WG1T, 2048, 1024);
  transpose_cvt<<<dim3(32, 32), 256, 0, stream>>>(Wg2, WG2T, 1024, 1024);
  // WQQT[t][f] = sum_u Wq[u][t]*Wq_in[f][u]  (M=128, N=1024, K=128)
  gemm128<0, bf16, 128><<<dim3(1, 8), 256, 0, stream>>>(WQT, WQT, 128, 128, 128, WQINB, 128,
                                                        nullptr, WQQT, 1024, nullptr, nullptr, 0);
  // WOCT[f][d] = sum_t Wc[t][f]*Wo[d][t]     (M=1024, N=128, K=128)
  gemm128<0, bf16, 128><<<dim3(8, 1), 256, 0, stream>>>(WCT, WCT, 128, 128, 128, WOB, 128,
                                                        nullptr, WOCT, 128, nullptr, nullptr, 0);
  tokens_kernel<<<16384, 128, 0, stream>>>(exl, iml, affv, geg, geb, Wex, bex,
                                           gig, gib, Wim, bim, gag, gab, Waf, baf, TOK);
  // G1: qh = FFB @ WqqT + bqq  (M=16384, K=1024, N=128), 64-row tiles
  gemm128<0, bf16, 64><<<dim3(256, 1), 256, 0, stream>>>(FFB, FFB, 1024, 1024, 1024, WQQT, 1024,
                                                         BQQ, QH, 128, nullptr, nullptr, 0);
  // G2: kvh = TOK @ [Wk|Wv]T  (M=49152, K=128, N=256) -> summary slot
  gemm128<0, bf16, 128><<<dim3(384, 2), 256, 0, stream>>>(TOK, TOK, 128, 128, 128, WKVT, 128,
                                                          BKV, KVH, 256, nullptr, nullptr, 0);
  attn_kernel<<<16384, 128, 0, stream>>>(QH, KVH, APRE, out_attw);
  // G3: ctx = APRE @ WocT + boc  (M=16384, K=128, N=1024) -> refined slot (bf16)
  gemm128<0, bf16, 128><<<dim3(128, 8), 256, 0, stream>>>(APRE, APRE, 128, 128, 128, WOCT, 128,
                                                          BOC, CTX, 1024, nullptr, nullptr, 0);
  // G5: gate_h = gelu([FFB|CTX] @ Wg1T + bg1)  (K=2048) -> summary slot (kvh dead)
  gemm256<1, bf16><<<dim3(64, 4), 512, 0, stream>>>(FFB, CTX, 1024, 1024, 1024, WG1T, 2048,
                                                    bg1, GATEH, 1024, nullptr, nullptr, 0);
  // G6: pre = FFB + sigmoid(gate_h @ Wg2T + bg2) * ctx -> PRE (elem-wise alias of FFB)
  gemm256<2, bf16><<<dim3(64, 4), 512, 0, stream>>>(GATEH, GATEH, 1024, 1024, 1024, WG2T, 1024,
                                                    bg2, PRE, 1024, FFB, CTX, 1024);
  // G4: summary = gelu(TOK @ WsT + bs)  (K=384) -> summary fp32 final (gateh dead)
  gemm256<1, float><<<dim3(64, 4), 512, 0, stream>>>(TOK, TOK, 384, 384, 384, WST, 384,
                                                     bs, out_summary, 1024, nullptr, nullptr, 0);
  // final LN: PRE bf16 -> refined fp32 (ctx dead)
  ln_out_kernel<<<16384, 256, 0, stream>>>(PRE, lng, lnb, out_refined);
}

// Round 2
// 592.126 us; speedup vs baseline: 1.0213x; 1.0213x over previous
//
#include <hip/hip_runtime.h>
#include <hip/hip_bf16.h>
#include <stdint.h>

// EmotionTriadFusion on MI355X — Round 7: true 8-phase gemm256 schedule.
// B=16384, F=1024, E=28, A=2, T=128, H=4, HD=32. fp32 I/O, bf16 MFMA internals.
//
// R6 (604us): coarse 2-phase gemm256 hit 29% MfmaUtil / 731 TF — the known
// "2-phase" plateau. R7 ports the verified 8-phase template: per K-tile 4
// quadrant-phases x 16 MFMA; per phase {ds_reads || stage 1 half-tile ->
// barrier -> lgkmcnt(0) -> setprio(1) MFMA setprio(0) -> barrier}; counted
// vmcnt(4) only at phases 4/8 (derived: 12 outstanding, need oldest 8).
// B-n0 frags held in regs across the tile -> 24 ds_read_b128/wave/K-tile.
// Half-tile staged into the slot freed exactly one phase earlier:
//   ph0:A-lo(odd) ph1:A-hi(odd) ph2:B-lo(+2) ph3:B-hi(+2)+W1
//   ph4:A-lo(+2)  ph5:A-hi(+2)  ph6:B-lo(+3) ph7:B-hi(+3)+W2
// Also: 5 transpose launches fused into transpose_all (launch-gap recovery).
//
// Pipeline:
//  ffb_convert: ff fp32 -> FFB bf16 (ws)
//  prep_small : WKVT/BKV/BQQ/BOC + bf16 converts of Wq_in, Wo
//  transpose_all: WQT, WCT, WST, WG1T, WG2T (coalesced, LDS 32x33, one launch)
//  fold GEMMs : WQQT = WQT @ WQINB^T ; WOCT = WCT @ WOB^T   (gemm128)
//  tokens  : softmax(28)->LN->(28->128)matmul->GELU x2 + affect -> TOK bf16
//  G1 qh   = FFB @ WqqT           M=16384 K=1024 N=128   -> QH bf16 (MT=64)
//  G2 kvh  = TOK @ [Wk|Wv]T       M=49152 K=128  N=256   -> summary slot
//  attn    -> attw fp32 (d_out) + APRE bf16 (ws)
//  G3 ctx  = APRE @ WocT          M=16384 K=128  N=1024  -> refined slot (bf16)
//  G5 gh   = gelu([FFB|CTX]@Wg1T) M=16384 K=2048 N=1024  -> summary (gemm256)
//  G6 pre  = FFB + sigmoid(gh@Wg2T)*ctx -> PRE bf16      (gemm256, aliases FFB)
//  G4 summ = gelu(TOK @ WsT)      M=16384 K=384  N=1024  -> summary f32 (gemm256)
//  ln      : LayerNorm(1024) PRE bf16 -> refined fp32 (final)

using bf16 = __hip_bfloat16;
typedef __bf16 bf16x8 __attribute__((ext_vector_type(8)));
typedef float f32x4 __attribute__((ext_vector_type(4)));

__device__ __forceinline__ float b2f(bf16 x) { return __bfloat162float(x); }
__device__ __forceinline__ bf16 f2b(float x) { return __float2bfloat16(x); }

__device__ __forceinline__ float fast_tanh(float y) {
  float z = fabsf(y);
  float t = __expf(-2.f * z);
  float r = (1.f - t) / (1.f + t);
  return copysignf(r, y);
}
__device__ __forceinline__ float gelu_f(float x) {
  return 0.5f * x * (1.f + fast_tanh(0.7978845608028654f * (x + 0.044715f * x * x * x)));
}
__device__ __forceinline__ float sigmoid_f(float v) {
  return 1.f / (1.f + __expf(-v));
}

__device__ __forceinline__ void async_ld16(const void* g, void* l) {
  using GP = const __attribute__((address_space(1))) uint32_t*;
  using LP = __attribute__((address_space(3))) uint32_t*;
  __builtin_amdgcn_global_load_lds((GP)g, (LP)l, 16, 0, 0);
}

// ---------------------------------------------------------------------------
__global__ void ffb_convert(const float* __restrict__ src, bf16* __restrict__ dst) {
  size_t i = ((size_t)blockIdx.x * 256 + threadIdx.x) * 4;
  float4 v = *reinterpret_cast<const float4*>(src + i);
  ushort4 o;
  o.x = __builtin_bit_cast(unsigned short, f2b(v.x));
  o.y = __builtin_bit_cast(unsigned short, f2b(v.y));
  o.z = __builtin_bit_cast(unsigned short, f2b(v.z));
  o.w = __builtin_bit_cast(unsigned short, f2b(v.w));
  *reinterpret_cast<ushort4*>(dst + i) = o;
}

// ---------------------------------------------------------------------------
// gemm128: tile MTx128, BK=64, 4 waves, for small/odd GEMMs (G1,G2,G3,folds).
// ---------------------------------------------------------------------------
template <int EPI, typename OutT, int MT>
__launch_bounds__(256)
__global__ void gemm128(const bf16* A0, const bf16* A1, int ksplit, int lda0, int lda1,
                        const bf16* __restrict__ BT, int K,
                        const float* __restrict__ bias,
                        OutT* out, int ldo,
                        const bf16* ffp, const bf16* ctxp, int ldfc)
{
  constexpr int MIC = MT / 32;
  __shared__ uint16_t smA[MT * 64];
  __shared__ uint16_t smB[128 * 64];
  const int tid = threadIdx.x;
  const int w = tid >> 6;
  const int l = tid & 63;
  const int m0 = blockIdx.x * MT;
  const int n0 = blockIdx.y * 128;
  const int wr = w >> 1, wc = w & 1;
  const int lrow = l & 15, lquad = l >> 4;
  const int rb = w * 8 + (l >> 3);
  const int cpos = l & 7;

  const f32x4 vzero = {0.f, 0.f, 0.f, 0.f};
  f32x4 acc[MIC][4];
#pragma unroll
  for (int i = 0; i < MIC; i++)
#pragma unroll
    for (int j = 0; j < 4; j++) acc[i][j] = vzero;

  for (int k0 = 0; k0 < K; k0 += 64) {
    __syncthreads();
#pragma unroll
    for (int i = 0; i < MIC; i++) {
      int row = i * 32 + rb;
      int cg = cpos ^ (row & 7);
      int kcol = k0 + cg * 8;
      const bf16* gp = (kcol < ksplit)
                           ? (A0 + (size_t)(m0 + row) * lda0 + kcol)
                           : (A1 + (size_t)(m0 + row) * lda1 + (kcol - ksplit));
      async_ld16(gp, &smA[(i * 32 + w * 8) * 64]);
    }
#pragma unroll
    for (int i = 0; i < 4; i++) {
      int row = i * 32 + rb;
      int cg = cpos ^ (row & 7);
      const bf16* gq = BT + (size_t)(n0 + row) * K + k0 + cg * 8;
      async_ld16(gq, &smB[(i * 32 + w * 8) * 64]);
    }
    __syncthreads();
#pragma unroll
    for (int kk = 0; kk < 2; kk++) {
      bf16x8 af[MIC], bfr[4];
      const int cc = kk * 4 + lquad;
#pragma unroll
      for (int mi = 0; mi < MIC; mi++) {
        int r = wr * (MT / 2) + mi * 16 + lrow;
        af[mi] = *(const bf16x8*)&smA[r * 64 + ((cc ^ (r & 7)) << 3)];
      }
#pragma unroll
      for (int ni = 0; ni < 4; ni++) {
        int r = wc * 64 + ni * 16 + lrow;
        bfr[ni] = *(const bf16x8*)&smB[r * 64 + ((cc ^ (r & 7)) << 3)];
      }
#pragma unroll
      for (int mi = 0; mi < MIC; mi++)
#pragma unroll
        for (int ni = 0; ni < 4; ni++)
          acc[mi][ni] =
              __builtin_amdgcn_mfma_f32_16x16x32_bf16(af[mi], bfr[ni], acc[mi][ni], 0, 0, 0);
    }
  }

#pragma unroll
  for (int mi = 0; mi < MIC; mi++) {
#pragma unroll
    for (int ni = 0; ni < 4; ni++) {
#pragma unroll
      for (int r = 0; r < 4; r++) {
        int row = m0 + wr * (MT / 2) + mi * 16 + lquad * 4 + r;
        int col = n0 + wc * 64 + ni * 16 + lrow;
        float v = acc[mi][ni][r] + (bias ? bias[col] : 0.f);
        if (EPI == 1) v = gelu_f(v);
        if (EPI == 2) {
          float gate = sigmoid_f(v);
          size_t fo = (size_t)row * ldfc + col;
          v = b2f(ffp[fo]) + gate * b2f(ctxp[fo]);
        }
        if constexpr (__is_same(OutT, float))
          out[(size_t)row * ldo + col] = v;
        else
          out[(size_t)row * ldo + col] = f2b(v);
      }
    }
  }
}

// ---------------------------------------------------------------------------
// gemm256: 256x256 tile, BK=64, 512 thr = 8 waves (2Mx4N), wave = 128x64.
// 8-phase schedule (see header comment). LDS 128KiB double buffer.
// ---------------------------------------------------------------------------
template <int EPI, typename OutT>
__launch_bounds__(512, 2)
__global__ void gemm256(const bf16* A0, const bf16* A1, int ksplit, int lda0, int lda1,
                        const bf16* __restrict__ BT, int K,
                        const float* __restrict__ bias,
                        OutT* out, int ldo,
                        const bf16* ffp, const bf16* ctxp, int ldfc)
{
  __shared__ uint16_t smA[2][256 * 64];
  __shared__ uint16_t smB[2][256 * 64];
  const int tid = threadIdx.x;
  const int w = tid >> 6;       // wave 0..7
  const int l = tid & 63;
  const int m0 = blockIdx.x * 256;
  const int n0 = blockIdx.y * 256;
  const int wr = w >> 2;        // M-half 0..1
  const int wc = w & 3;         // N-quarter 0..3
  const int lrow = l & 15, lquad = l >> 4;
  const int rb = tid >> 3;      // staging row within 64-row group (0..63)
  const int cpos = tid & 7;     // staging 16B-chunk position
  const int NT = K >> 6;        // K-tiles (even for all our K)

  const f32x4 vzero = {0.f, 0.f, 0.f, 0.f};
  f32x4 acc[8][4];
#pragma unroll
  for (int mi = 0; mi < 8; mi++)
#pragma unroll
    for (int ni = 0; ni < 4; ni++) acc[mi][ni] = vzero;

  // stage one half-tile (128 rows x 64 K) of A or B: 2 x global_load_lds.
  // LDS(row, chunk p) = global(row, p ^ (row&7)); dest wave-uniform + lane*16.
  auto stageA = [&](int buf, int half, int tt) {
    if (tt >= NT) return;
    const int k0 = tt << 6;
    const bf16* Ab; int la, kc;
    if (k0 < ksplit) { Ab = A0; la = lda0; kc = k0; }
    else             { Ab = A1; la = lda1; kc = k0 - ksplit; }
#pragma unroll
    for (int i = 0; i < 2; i++) {
      const int row = half * 128 + i * 64 + rb;
      const int cg = cpos ^ (row & 7);
      async_ld16(Ab + (size_t)(m0 + row) * la + kc + cg * 8,
                 &smA[buf][(half * 128 + i * 64 + w * 8) * 64]);
    }
  };
  auto stageB = [&](int buf, int half, int tt) {
    if (tt >= NT) return;
    const int k0 = tt << 6;
#pragma unroll
    for (int i = 0; i < 2; i++) {
      const int row = half * 128 + i * 64 + rb;
      const int cg = cpos ^ (row & 7);
      async_ld16(BT + (size_t)(n0 + row) * K + k0 + cg * 8,
                 &smB[buf][(half * 128 + i * 64 + w * 8) * 64]);
    }
  };

  bf16x8 a[4][2], b0[2][2], b1[2][2];

  auto rdA = [&](int buf, int miBlk) {  // 8 ds_read_b128
#pragma unroll
    for (int mi = 0; mi < 4; mi++)
#pragma unroll
      for (int kk = 0; kk < 2; kk++) {
        int r = wr * 128 + miBlk * 64 + mi * 16 + lrow;
        int cc = kk * 4 + lquad;
        a[mi][kk] = *(const bf16x8*)&smA[buf][r * 64 + ((cc ^ (r & 7)) << 3)];
      }
  };
  auto rdB0 = [&](int buf) {  // 4 ds_read_b128 (ni 0,1)
#pragma unroll
    for (int ni = 0; ni < 2; ni++)
#pragma unroll
      for (int kk = 0; kk < 2; kk++) {
        int r = wc * 64 + ni * 16 + lrow;
        int cc = kk * 4 + lquad;
        b0[ni][kk] = *(const bf16x8*)&smB[buf][r * 64 + ((cc ^ (r & 7)) << 3)];
      }
  };
  auto rdB1 = [&](int buf) {  // 4 ds_read_b128 (ni 2,3)
#pragma unroll
    for (int ni = 0; ni < 2; ni++)
#pragma unroll
      for (int kk = 0; kk < 2; kk++) {
        int r = wc * 64 + 32 + ni * 16 + lrow;
        int cc = kk * 4 + lquad;
        b1[ni][kk] = *(const bf16x8*)&smB[buf][r * 64 + ((cc ^ (r & 7)) << 3)];
      }
  };
  auto mm = [&](int miBlk, int niBlk, bf16x8 (&bf)[2][2]) {  // 16 MFMA
#pragma unroll
    for (int mi = 0; mi < 4; mi++)
#pragma unroll
      for (int ni = 0; ni < 2; ni++)
#pragma unroll
        for (int kk = 0; kk < 2; kk++)
          acc[miBlk * 4 + mi][niBlk * 2 + ni] = __builtin_amdgcn_mfma_f32_16x16x32_bf16(
              a[mi][kk], bf[ni][kk], acc[miBlk * 4 + mi][niBlk * 2 + ni], 0, 0, 0);
  };

  auto fence_mid = [&]() {
    __builtin_amdgcn_s_barrier();
    asm volatile("s_waitcnt lgkmcnt(0)" ::: "memory");
    __builtin_amdgcn_sched_barrier(0);
    __builtin_amdgcn_s_setprio(1);
  };
  auto fence_end = [&](bool wait4) {
    __builtin_amdgcn_s_setprio(0);
    __builtin_amdgcn_sched_barrier(0);
    if (wait4) asm volatile("s_waitcnt vmcnt(4)" ::: "memory");
    __builtin_amdgcn_s_barrier();
    __builtin_amdgcn_sched_barrier(0);
  };

  // prologue: tile0 (buf0) fully + tile1 (buf1) B-halves = 12 loads;
  // vmcnt(4) -> tile0's 8 oldest loads landed.
  stageB(0, 0, 0); stageB(0, 1, 0); stageA(0, 0, 0); stageA(0, 1, 0);
  stageB(1, 0, 1); stageB(1, 1, 1);
  asm volatile("s_waitcnt vmcnt(4)" ::: "memory");
  __builtin_amdgcn_s_barrier();
  __builtin_amdgcn_sched_barrier(0);

  const int NI = NT >> 1;
#pragma unroll 1
  for (int t = 0; t < NI; ++t) {
    const int To = 2 * t + 1;
    const int Tn = 2 * t + 2;
    // ---- tile even (buf0) ----
    // ph0: q(m-lo,n0): rdA lo + rdB0 ; stage A-lo(odd)->buf1
    rdA(0, 0); rdB0(0);
    stageA(1, 0, To);
    fence_mid(); mm(0, 0, b0); fence_end(false);
    // ph1: q(m-lo,n1): rdB1 ; stage A-hi(odd)->buf1
    rdB1(0);
    stageA(1, 1, To);
    fence_mid(); mm(0, 1, b1); fence_end(false);
    // ph2: q(m-hi,n1): rdA hi ; stage B-lo(Tn)->buf0  (B-lo free after ph1)
    rdA(0, 1);
    stageB(0, 0, Tn);
    fence_mid(); mm(1, 1, b1); fence_end(false);
    // ph3: q(m-hi,n0): b0 held ; stage B-hi(Tn)->buf0 ; W1: tile odd landed
    stageB(0, 1, Tn);
    fence_mid(); mm(1, 0, b0); fence_end(true);
    // ---- tile odd (buf1) ----
    // ph4: rdA lo + rdB0 ; stage A-lo(Tn)->buf0  (A free after ph2)
    rdA(1, 0); rdB0(1);
    stageA(0, 0, Tn);
    fence_mid(); mm(0, 0, b0); fence_end(false);
    // ph5: rdB1 ; stage A-hi(Tn)->buf0
    rdB1(1);
    stageA(0, 1, Tn);
    fence_mid(); mm(0, 1, b1); fence_end(false);
    // ph6: rdA hi ; stage B-lo(Tn+1)->buf1  (buf1 B free after ph5)
    rdA(1, 1);
    stageB(1, 0, Tn + 1);
    fence_mid(); mm(1, 1, b1); fence_end(false);
    // ph7: b0 held ; stage B-hi(Tn+1)->buf1 ; W2: tile Tn landed
    stageB(1, 1, Tn + 1);
    fence_mid(); mm(1, 0, b0); fence_end(true);
  }

  // epilogue: C/D layout col=lane&15, row=(lane>>4)*4+reg
#pragma unroll
  for (int mi = 0; mi < 8; mi++) {
#pragma unroll
    for (int ni = 0; ni < 4; ni++) {
#pragma unroll
      for (int r = 0; r < 4; r++) {
        int row = m0 + wr * 128 + mi * 16 + lquad * 4 + r;
        int col = n0 + wc * 64 + ni * 16 + lrow;
        float v = acc[mi][ni][r] + (bias ? bias[col] : 0.f);
        if (EPI == 1) v = gelu_f(v);
        if (EPI == 2) {
          float gate = sigmoid_f(v);
          size_t fo = (size_t)row * ldfc + col;
          v = b2f(ffp[fo]) + gate * b2f(ctxp[fo]);
        }
        if constexpr (__is_same(OutT, float))
          out[(size_t)row * ldo + col] = v;
        else
          out[(size_t)row * ldo + col] = f2b(v);
      }
    }
  }
}

// ---------------------------------------------------------------------------
// All weight transposes (fp32 -> bf16, out[c][r] = in[r][c]) in ONE launch.
// 32x32 tile/block via LDS 32x33. Total blocks = 16+128+384+2048+1024 = 3600.
// ---------------------------------------------------------------------------
__global__ void transpose_all(const float* __restrict__ Wq, const float* __restrict__ Wc,
                              const float* __restrict__ Ws, const float* __restrict__ Wg1,
                              const float* __restrict__ Wg2,
                              bf16* WQT, bf16* WCT, bf16* WST, bf16* WG1T, bf16* WG2T)
{
  __shared__ float tile[32][33];
  int bid = blockIdx.x;
  const float* in; bf16* outp; int R, C, bx, by;
  if (bid < 16)              { in = Wq;  outp = WQT;  R = 128;  C = 128;  bx = bid & 3;  by = bid >> 2; }
  else if ((bid -= 16) < 128)  { in = Wc;  outp = WCT;  R = 128;  C = 1024; bx = bid & 31; by = bid >> 5; }
  else if ((bid -= 128) < 384) { in = Ws;  outp = WST;  R = 384;  C = 1024; bx = bid & 31; by = bid >> 5; }
  else if ((bid -= 384) < 2048){ in = Wg1; outp = WG1T; R = 2048; C = 1024; bx = bid & 31; by = bid >> 5; }
  else { bid -= 2048;            in = Wg2; outp = WG2T; R = 1024; C = 1024; bx = bid & 31; by = bid >> 5; }
  const int tx = threadIdx.x & 31, ty = threadIdx.x >> 5;  // ty in [0,8)
  const int c0 = bx * 32, r0 = by * 32;
#pragma unroll
  for (int i = 0; i < 4; i++) {
    int r = ty + i * 8;
    tile[r][tx] = in[(size_t)(r0 + r) * C + c0 + tx];
  }
  __syncthreads();
#pragma unroll
  for (int i = 0; i < 4; i++) {
    int c = ty + i * 8;
    outp[(size_t)(c0 + c) * R + r0 + tx] = f2b(tile[tx][c]);
  }
}

// ---------------------------------------------------------------------------
// Small prep: KV weight concat/transpose, folded biases, bf16 converts.
// ---------------------------------------------------------------------------
__global__ void prep_small(
    const float* __restrict__ Wk, const float* __restrict__ bk,
    const float* __restrict__ Wv, const float* __restrict__ bv,
    const float* __restrict__ Wq_in, const float* __restrict__ bq_in,
    const float* __restrict__ Wq, const float* __restrict__ bq,
    const float* __restrict__ Wo, const float* __restrict__ bo,
    const float* __restrict__ Wc, const float* __restrict__ bc,
    bf16* WKVT, float* BKV, float* BQQ, float* BOC, bf16* WQINB, bf16* WOB)
{
  int idx = blockIdx.x * 256 + threadIdx.x;
  if (idx < 32768) {
    int n = idx >> 7, k = idx & 127;
    WKVT[idx] = f2b((n < 128) ? Wk[k * 128 + n] : Wv[k * 128 + (n - 128)]);
    return;
  }
  idx -= 32768;
  if (idx < 256) { BKV[idx] = (idx < 128) ? bk[idx] : bv[idx - 128]; return; }
  idx -= 256;
  if (idx < 128) {
    float s = bq[idx];
    for (int u = 0; u < 128; u++) s += bq_in[u] * Wq[u * 128 + idx];
    BQQ[idx] = s;
    return;
  }
  idx -= 128;
  if (idx < 1024) {
    float s = bc[idx];
    for (int t = 0; t < 128; t++) s += bo[t] * Wc[t * 1024 + idx];
    BOC[idx] = s;
    return;
  }
  idx -= 1024;
  if (idx < 131072) { WQINB[idx] = f2b(Wq_in[idx]); return; }
  idx -= 131072;
  if (idx < 16384) { WOB[idx] = f2b(Wo[idx]); return; }
}

// ---------------------------------------------------------------------------
__device__ __forceinline__ void emb28(const float* __restrict__ logits,
                                      const float* __restrict__ g,
                                      const float* __restrict__ bb,
                                      const float* __restrict__ W,
                                      const float* __restrict__ wb,
                                      bf16* __restrict__ out, int t,
                                      float* sv, float* sp)
{
  if (t < 28) sv[t] = logits[t];
  __syncthreads();
  float mx = sv[0];
#pragma unroll
  for (int e = 1; e < 28; e++) mx = fmaxf(mx, sv[e]);
  if (t < 28) sp[t] = __expf(sv[t] - mx);
  __syncthreads();
  float sum = 0.f;
#pragma unroll
  for (int e = 0; e < 28; e++) sum += sp[e];
  float inv = 1.f / sum;
  float sp2 = 0.f;
#pragma unroll
  for (int e = 0; e < 28; e++) { float p = sp[e] * inv; sp2 += p * p; }
  const float mean = 1.f / 28.f;
  float var = sp2 * (1.f / 28.f) - mean * mean;
  float rstd = rsqrtf(var + 1e-5f);
  __syncthreads();
  if (t < 28) sp[t] = (sp[t] * inv - mean) * rstd * g[t] + bb[t];
  __syncthreads();
  float acc = wb[t];
#pragma unroll
  for (int e = 0; e < 28; e++) acc += sp[e] * W[e * 128 + t];
  out[t] = f2b(gelu_f(acc));
  __syncthreads();
}

__global__ void tokens_kernel(
    const float* __restrict__ exl, const float* __restrict__ iml, const float* __restrict__ affv,
    const float* __restrict__ geg, const float* __restrict__ geb,
    const float* __restrict__ Wex, const float* __restrict__ bex,
    const float* __restrict__ gig, const float* __restrict__ gib,
    const float* __restrict__ Wim, const float* __restrict__ bim,
    const float* __restrict__ gag, const float* __restrict__ gab,
    const float* __restrict__ Waf, const float* __restrict__ baf,
    bf16* __restrict__ tokens)
{
  __shared__ float sv[28], sp[28];
  const int b = blockIdx.x, t = threadIdx.x;
  bf16* trow = tokens + (size_t)b * 384;
  emb28(exl + (size_t)b * 28, geg, geb, Wex, bex, trow, t, sv, sp);
  emb28(iml + (size_t)b * 28, gig, gib, Wim, bim, trow + 128, t, sv, sp);
  float a0 = affv[(size_t)b * 2 + 0];
  float a1 = affv[(size_t)b * 2 + 1];
  float m = 0.5f * (a0 + a1);
  float d0 = a0 - m, d1 = a1 - m;
  float var = 0.5f * (d0 * d0 + d1 * d1);
  float rstd = rsqrtf(var + 1e-5f);
  float l0 = d0 * rstd * gag[0] + gab[0];
  float l1 = d1 * rstd * gag[1] + gab[1];
  float acc = baf[t] + l0 * Waf[t] + l1 * Waf[128 + t];
  trow[256 + t] = f2b(gelu_f(acc));
}

// ---------------------------------------------------------------------------
__global__ void attn_kernel(const bf16* __restrict__ qh, const bf16* __restrict__ kvh,
                            bf16* __restrict__ apre, float* __restrict__ attw)
{
  const int b = blockIdx.x, t = threadIdx.x;  // 128 threads
  float q = b2f(qh[(size_t)b * 128 + t]);
  const bf16* kv = kvh + (size_t)b * 3 * 256;
  float s[3], v[3];
#pragma unroll
  for (int i = 0; i < 3; i++) {
    float k = b2f(kv[i * 256 + t]);
    v[i] = b2f(kv[i * 256 + 128 + t]);
    float r = q * k;
#pragma unroll
    for (int off = 16; off > 0; off >>= 1) r += __shfl_down(r, off, 32);
    r = __shfl(r, 0, 32);
    s[i] = r * 0.17677669529663687f;  // 1/sqrt(32)
  }
  float mx = fmaxf(s[0], fmaxf(s[1], s[2]));
  float e0 = __expf(s[0] - mx), e1 = __expf(s[1] - mx), e2 = __expf(s[2] - mx);
  float inv = 1.f / (e0 + e1 + e2);
  float w0 = e0 * inv, w1 = e1 * inv, w2 = e2 * inv;
  apre[(size_t)b * 128 + t] = f2b(w0 * v[0] + w1 * v[1] + w2 * v[2]);
  __shared__ float aw[4][3];
  if ((t & 31) == 0) { int h = t >> 5; aw[h][0] = w0; aw[h][1] = w1; aw[h][2] = w2; }
  __syncthreads();
  if (t < 3)
    attw[(size_t)b * 3 + t] = 0.25f * (aw[0][t] + aw[1][t] + aw[2][t] + aw[3][t]);
}

// ---------------------------------------------------------------------------
__global__ void ln_out_kernel(const bf16* __restrict__ x, const float* __restrict__ g,
                              const float* __restrict__ bb, float* __restrict__ out)
{
  const int row = blockIdx.x, t = threadIdx.x;
  const bf16* xr = x + (size_t)row * 1024;
  ushort4 u = *reinterpret_cast<const ushort4*>(xr + t * 4);
  float v0 = __uint_as_float((uint32_t)u.x << 16);
  float v1 = __uint_as_float((uint32_t)u.y << 16);
  float v2 = __uint_as_float((uint32_t)u.z << 16);
  float v3 = __uint_as_float((uint32_t)u.w << 16);
  float s = v0 + v1 + v2 + v3;
  float s2 = v0 * v0 + v1 * v1 + v2 * v2 + v3 * v3;
#pragma unroll
  for (int off = 32; off > 0; off >>= 1) {
    s += __shfl_down(s, off, 64);
    s2 += __shfl_down(s2, off, 64);
  }
  __shared__ float ls[4], ls2[4];
  const int w = t >> 6;
  if ((t & 63) == 0) { ls[w] = s; ls2[w] = s2; }
  __syncthreads();
  float S = ls[0] + ls[1] + ls[2] + ls[3];
  float S2 = ls2[0] + ls2[1] + ls2[2] + ls2[3];
  float mean = S * (1.f / 1024.f);
  float var = S2 * (1.f / 1024.f) - mean * mean;
  float rstd = rsqrtf(var + 1e-5f);
  const int c = t * 4;
  float4 o;
  o.x = (v0 - mean) * rstd * g[c + 0] + bb[c + 0];
  o.y = (v1 - mean) * rstd * g[c + 1] + bb[c + 1];
  o.z = (v2 - mean) * rstd * g[c + 2] + bb[c + 2];
  o.w = (v3 - mean) * rstd * g[c + 3] + bb[c + 3];
  *reinterpret_cast<float4*>(out + (size_t)row * 1024 + c) = o;
}

// ---------------------------------------------------------------------------
extern "C" void kernel_launch(void* const* d_in, const int* in_sizes, int n_in,
                              void* d_out, int out_size, void* d_ws, size_t ws_size,
                              hipStream_t stream)
{
  const float* ff   = (const float*)d_in[0];
  const float* exl  = (const float*)d_in[1];
  const float* iml  = (const float*)d_in[2];
  const float* affv = (const float*)d_in[3];
  const float* geg = (const float*)d_in[4],  *geb = (const float*)d_in[5];
  const float* Wex = (const float*)d_in[6],  *bex = (const float*)d_in[7];
  const float* gig = (const float*)d_in[8],  *gib = (const float*)d_in[9];
  const float* Wim = (const float*)d_in[10], *bim = (const float*)d_in[11];
  const float* gag = (const float*)d_in[12], *gab = (const float*)d_in[13];
  const float* Waf = (const float*)d_in[14], *baf = (const float*)d_in[15];
  const float* Wq_in = (const float*)d_in[16], *bq_in = (const float*)d_in[17];
  const float* Wq = (const float*)d_in[18], *bq = (const float*)d_in[19];
  const float* Wk = (const float*)d_in[20], *bk = (const float*)d_in[21];
  const float* Wv = (const float*)d_in[22], *bv = (const float*)d_in[23];
  const float* Wo = (const float*)d_in[24], *bo = (const float*)d_in[25];
  const float* Wc = (const float*)d_in[26], *bc = (const float*)d_in[27];
  const float* Ws = (const float*)d_in[28], *bs = (const float*)d_in[29];
  const float* Wg1 = (const float*)d_in[30], *bg1 = (const float*)d_in[31];
  const float* Wg2 = (const float*)d_in[32], *bg2 = (const float*)d_in[33];
  const float* lng = (const float*)d_in[34], *lnb = (const float*)d_in[35];

  // workspace layout (bytes); peak = 62,199,296 (~59.3 MB)
  char* ws = (char*)d_ws;
  bf16*  WKVT = (bf16*)(ws + 0);         //  32768 el bf16
  float* BKV  = (float*)(ws + 65536);    //    256 el f32
  bf16*  WQQT = (bf16*)(ws + 66560);     // 131072 el bf16
  float* BQQ  = (float*)(ws + 328704);   //    128 el f32
  bf16*  WOCT = (bf16*)(ws + 329216);    // 131072 el bf16
  float* BOC  = (float*)(ws + 591360);   //   1024 el f32
  bf16*  WST  = (bf16*)(ws + 595456);    // 393216 el bf16
  bf16*  WG1T = (bf16*)(ws + 1381888);   // 2097152 el bf16
  bf16*  WG2T = (bf16*)(ws + 5576192);   // 1048576 el bf16
  bf16*  FFB  = (bf16*)(ws + 7673344);   // B*1024 (live: convert..G6)
  bf16*  PRE  = (bf16*)(ws + 7673344);   // B*1024, aliases FFB elem-wise (G6..ln)
  bf16*  TOK  = (bf16*)(ws + 41227776);  // B*384  (live: tokens..G4)
  bf16*  QH   = (bf16*)(ws + 53810688);  // B*128  (live: G1..attn)
  bf16*  APRE = (bf16*)(ws + 58004992);  // B*128  (live: attn..G3)

  // prep temporaries carved from the (not-yet-live) QH slot (4 MB avail):
  bf16* WQT   = (bf16*)(ws + 53810688);            //  16384 el (Wq^T)
  bf16* WOB   = (bf16*)(ws + 53810688 + 32768);    //  16384 el (Wo bf16)
  bf16* WQINB = (bf16*)(ws + 53810688 + 65536);    // 131072 el (Wq_in bf16)
  bf16* WCT   = (bf16*)(ws + 53810688 + 327680);   // 131072 el (Wc^T)

  float* outp = (float*)d_out;
  float* out_refined = outp;             // B*1024 f32; hosts CTX bf16 G3..G6
  float* out_attw    = outp + 16777216;  // B*3 f32
  float* out_summary = outp + 16826368;  // B*1024 f32; hosts KVH bf16 G2..attn, GATEH bf16 G5..G6
  bf16* CTX   = (bf16*)out_refined;
  bf16* KVH   = (bf16*)out_summary;
  bf16* GATEH = (bf16*)out_summary;

  ffb_convert<<<16384, 256, 0, stream>>>(ff, FFB);
  prep_small<<<710, 256, 0, stream>>>(Wk, bk, Wv, bv, Wq_in, bq_in, Wq, bq,
                                      Wo, bo, Wc, bc, WKVT, BKV, BQQ, BOC, WQINB, WOB);
  transpose_all<<<3600, 256, 0, stream>>>(Wq, Wc, Ws, Wg1, Wg2, WQT, WCT, WST, WG1T, WG2T);
  // WQQT[t][f] = sum_u Wq[u][t]*Wq_in[f][u]  (M=128, N=1024, K=128)
  gemm128<0, bf16, 128><<<dim3(1, 8), 256, 0, stream>>>(WQT, WQT, 128, 128, 128, WQINB, 128,
                                                        nullptr, WQQT, 1024, nullptr, nullptr, 0);
  // WOCT[f][d] = sum_t Wc[t][f]*Wo[d][t]     (M=1024, N=128, K=128)
  gemm128<0, bf16, 128><<<dim3(8, 1), 256, 0, stream>>>(WCT, WCT, 128, 128, 128, WOB, 128,
                                                        nullptr, WOCT, 128, nullptr, nullptr, 0);
  tokens_kernel<<<16384, 128, 0, stream>>>(exl, iml, affv, geg, geb, Wex, bex,
                                           gig, gib, Wim, bim, gag, gab, Waf, baf, TOK);
  // G1: qh = FFB @ WqqT + bqq  (M=16384, K=1024, N=128), 64-row tiles
  gemm128<0, bf16, 64><<<dim3(256, 1), 256, 0, stream>>>(FFB, FFB, 1024, 1024, 1024, WQQT, 1024,
                                                         BQQ, QH, 128, nullptr, nullptr, 0);
  // G2: kvh = TOK @ [Wk|Wv]T  (M=49152, K=128, N=256) -> summary slot
  gemm128<0, bf16, 128><<<dim3(384, 2), 256, 0, stream>>>(TOK, TOK, 128, 128, 128, WKVT, 128,
                                                          BKV, KVH, 256, nullptr, nullptr, 0);
  attn_kernel<<<16384, 128, 0, stream>>>(QH, KVH, APRE, out_attw);
  // G3: ctx = APRE @ WocT + boc  (M=16384, K=128, N=1024) -> refined slot (bf16)
  gemm128<0, bf16, 128><<<dim3(128, 8), 256, 0, stream>>>(APRE, APRE, 128, 128, 128, WOCT, 128,
                                                          BOC, CTX, 1024, nullptr, nullptr, 0);
  // G5: gate_h = gelu([FFB|CTX] @ Wg1T + bg1)  (K=2048) -> summary slot (kvh dead)
  gemm256<1, bf16><<<dim3(64, 4), 512, 0, stream>>>(FFB, CTX, 1024, 1024, 1024, WG1T, 2048,
                                                    bg1, GATEH, 1024, nullptr, nullptr, 0);
  // G6: pre = FFB + sigmoid(gate_h @ Wg2T + bg2) * ctx -> PRE (elem-wise alias of FFB)
  gemm256<2, bf16><<<dim3(64, 4), 512, 0, stream>>>(GATEH, GATEH, 1024, 1024, 1024, WG2T, 1024,
                                                    bg2, PRE, 1024, FFB, CTX, 1024);
  // G4: summary = gelu(TOK @ WsT + bs)  (K=384) -> summary fp32 final (gateh dead)
  gemm256<1, float><<<dim3(64, 4), 512, 0, stream>>>(TOK, TOK, 384, 384, 384, WST, 384,
                                                     bs, out_summary, 1024, nullptr, nullptr, 0);
  // final LN: PRE bf16 -> refined fp32 (ctx dead)
  ln_out_kernel<<<16384, 256, 0, stream>>>(PRE, lng, lnb, out_refined);
}

// Round 3
// 568.759 us; speedup vs baseline: 1.0632x; 1.0411x over previous
//
#include <hip/hip_runtime.h>
#include <hip/hip_bf16.h>
#include <stdint.h>

// EmotionTriadFusion on MI355X — Round 8: launch-count 19 -> 9.
// B=16384, F=1024, E=28, A=2, T=128, H=4, HD=32. fp32 I/O, bf16 MFMA internals.
//
// R5/R6/R7 evidence: three different GEMM structures (128^2 4-wave, 256^2
// 2-phase, 256^2 8-phase) ALL give 27.9-29.1% MfmaUtil -> schedule is not the
// movable constraint at the 248-reg budget (ping-pong frags would cross the
// 256-reg occupancy cliff). Meanwhile R5->R6 (+6 launches) cost +47us total
// despite ~-50us of kernel-time wins, and R6->R7 (-4 launches) gave -12us:
// inter-launch overhead ~3-16us/launch dominates the unaccounted ~300us.
// R8: merge launches (ffb+tokens+transpose+prep -> preamble; 2 folds -> 1;
// G1+G2 -> 1) and keep the best-measured gemm256 (R6 schedule, 94.4us).
//
// Launches (9):
//  1 preamble  : ffb row + tokens row (16384 blk) | transposes (3600) | prep (710)
//  2 folds     : WQQT = WQT@WQINB^T (8 blk) + WOCT = WCT@WOB^T (8 blk)
//  3 g12       : G2 kvh = TOK@[Wk|Wv]T (768 blk) + G1 qh = FFB@WqqT (128 blk)
//  4 attn      -> attw fp32 (d_out) + APRE bf16 (ws)
//  5 G3 ctx    = APRE @ WocT          M=16384 K=128  N=1024  (gemm128)
//  6 G5 gh     = gelu([FFB|CTX]@Wg1T) M=16384 K=2048 N=1024  (gemm256)
//  7 G6 pre    = FFB + sigmoid(gh@Wg2T)*ctx -> PRE           (gemm256)
//  8 G4 summ   = gelu(TOK @ WsT)      M=16384 K=384  N=1024  (gemm256)
//  9 ln        : LayerNorm(1024) PRE bf16 -> refined fp32

using bf16 = __hip_bfloat16;
typedef __bf16 bf16x8 __attribute__((ext_vector_type(8)));
typedef float f32x4 __attribute__((ext_vector_type(4)));

__device__ __forceinline__ float b2f(bf16 x) { return __bfloat162float(x); }
__device__ __forceinline__ bf16 f2b(float x) { return __float2bfloat16(x); }

__device__ __forceinline__ float fast_tanh(float y) {
  float z = fabsf(y);
  float t = __expf(-2.f * z);
  float r = (1.f - t) / (1.f + t);
  return copysignf(r, y);
}
__device__ __forceinline__ float gelu_f(float x) {
  return 0.5f * x * (1.f + fast_tanh(0.7978845608028654f * (x + 0.044715f * x * x * x)));
}
__device__ __forceinline__ float sigmoid_f(float v) {
  return 1.f / (1.f + __expf(-v));
}

__device__ __forceinline__ void async_ld16(const void* g, void* l) {
  using GP = const __attribute__((address_space(1))) uint32_t*;
  using LP = __attribute__((address_space(3))) uint32_t*;
  __builtin_amdgcn_global_load_lds((GP)g, (LP)l, 16, 0, 0);
}

// ---------------------------------------------------------------------------
// gemm128 body as a __device__ function so multiple launch wrappers share it.
// Tile MTx128, BK=64, 4 waves 2x2, wave (MT/2)x64.
// ---------------------------------------------------------------------------
template <int EPI, typename OutT, int MT>
__device__ __forceinline__ void gemm128_dev(
    int bx, int by,
    const bf16* A0, const bf16* A1, int ksplit, int lda0, int lda1,
    const bf16* __restrict__ BT, int K,
    const float* __restrict__ bias,
    OutT* out, int ldo,
    const bf16* ffp, const bf16* ctxp, int ldfc)
{
  constexpr int MIC = MT / 32;
  __shared__ uint16_t smA[MT * 64];
  __shared__ uint16_t smB[128 * 64];
  const int tid = threadIdx.x;
  const int w = tid >> 6;
  const int l = tid & 63;
  const int m0 = bx * MT;
  const int n0 = by * 128;
  const int wr = w >> 1, wc = w & 1;
  const int lrow = l & 15, lquad = l >> 4;
  const int rb = w * 8 + (l >> 3);
  const int cpos = l & 7;

  const f32x4 vzero = {0.f, 0.f, 0.f, 0.f};
  f32x4 acc[MIC][4];
#pragma unroll
  for (int i = 0; i < MIC; i++)
#pragma unroll
    for (int j = 0; j < 4; j++) acc[i][j] = vzero;

  for (int k0 = 0; k0 < K; k0 += 64) {
    __syncthreads();
#pragma unroll
    for (int i = 0; i < MIC; i++) {
      int row = i * 32 + rb;
      int cg = cpos ^ (row & 7);
      int kcol = k0 + cg * 8;
      const bf16* gp = (kcol < ksplit)
                           ? (A0 + (size_t)(m0 + row) * lda0 + kcol)
                           : (A1 + (size_t)(m0 + row) * lda1 + (kcol - ksplit));
      async_ld16(gp, &smA[(i * 32 + w * 8) * 64]);
    }
#pragma unroll
    for (int i = 0; i < 4; i++) {
      int row = i * 32 + rb;
      int cg = cpos ^ (row & 7);
      const bf16* gq = BT + (size_t)(n0 + row) * K + k0 + cg * 8;
      async_ld16(gq, &smB[(i * 32 + w * 8) * 64]);
    }
    __syncthreads();
#pragma unroll
    for (int kk = 0; kk < 2; kk++) {
      bf16x8 af[MIC], bfr[4];
      const int cc = kk * 4 + lquad;
#pragma unroll
      for (int mi = 0; mi < MIC; mi++) {
        int r = wr * (MT / 2) + mi * 16 + lrow;
        af[mi] = *(const bf16x8*)&smA[r * 64 + ((cc ^ (r & 7)) << 3)];
      }
#pragma unroll
      for (int ni = 0; ni < 4; ni++) {
        int r = wc * 64 + ni * 16 + lrow;
        bfr[ni] = *(const bf16x8*)&smB[r * 64 + ((cc ^ (r & 7)) << 3)];
      }
#pragma unroll
      for (int mi = 0; mi < MIC; mi++)
#pragma unroll
        for (int ni = 0; ni < 4; ni++)
          acc[mi][ni] =
              __builtin_amdgcn_mfma_f32_16x16x32_bf16(af[mi], bfr[ni], acc[mi][ni], 0, 0, 0);
    }
  }

  // epilogue: C/D layout col=lane&15, row=(lane>>4)*4+reg
#pragma unroll
  for (int mi = 0; mi < MIC; mi++) {
#pragma unroll
    for (int ni = 0; ni < 4; ni++) {
#pragma unroll
      for (int r = 0; r < 4; r++) {
        int row = m0 + wr * (MT / 2) + mi * 16 + lquad * 4 + r;
        int col = n0 + wc * 64 + ni * 16 + lrow;
        float v = acc[mi][ni][r] + (bias ? bias[col] : 0.f);
        if (EPI == 1) v = gelu_f(v);
        if (EPI == 2) {
          float gate = sigmoid_f(v);
          size_t fo = (size_t)row * ldfc + col;
          v = b2f(ffp[fo]) + gate * b2f(ctxp[fo]);
        }
        if constexpr (__is_same(OutT, float))
          out[(size_t)row * ldo + col] = v;
        else
          out[(size_t)row * ldo + col] = f2b(v);
      }
    }
  }
}

// Standalone gemm128 (used for G3).
template <int EPI, typename OutT, int MT>
__launch_bounds__(256)
__global__ void gemm128_k(const bf16* A0, const bf16* A1, int ksplit, int lda0, int lda1,
                          const bf16* __restrict__ BT, int K,
                          const float* __restrict__ bias,
                          OutT* out, int ldo,
                          const bf16* ffp, const bf16* ctxp, int ldfc)
{
  gemm128_dev<EPI, OutT, MT>(blockIdx.x, blockIdx.y, A0, A1, ksplit, lda0, lda1,
                             BT, K, bias, out, ldo, ffp, ctxp, ldfc);
}

// Both weight folds in one launch (16 blocks).
__launch_bounds__(256)
__global__ void folds_k(const bf16* WQT, const bf16* WQINB, bf16* WQQT,
                        const bf16* WCT, const bf16* WOB, bf16* WOCT)
{
  int bid = blockIdx.x;
  if (bid < 8) {
    // WQQT[t][f] = sum_u WQT[t][u]*WQINB[f][u]  (M=128, N=1024, K=128)
    gemm128_dev<0, bf16, 128>(0, bid, WQT, WQT, 128, 128, 128, WQINB, 128,
                              nullptr, WQQT, 1024, nullptr, nullptr, 0);
  } else {
    // WOCT[f][d] = sum_t WCT[f][t]*WOB[d][t]    (M=1024, N=128, K=128)
    gemm128_dev<0, bf16, 128>(bid - 8, 0, WCT, WCT, 128, 128, 128, WOB, 128,
                              nullptr, WOCT, 128, nullptr, nullptr, 0);
  }
}

// G2 (768 blocks) + G1 (128 blocks) in one launch.
__launch_bounds__(256)
__global__ void g12_k(const bf16* FFB, const bf16* WQQT, const float* BQQ, bf16* QH,
                      const bf16* TOK, const bf16* WKVT, const float* BKV, bf16* KVH)
{
  int bid = blockIdx.x;
  if (bid < 768) {
    // G2: kvh = TOK @ [Wk|Wv]T  (M=49152, K=128, N=256)
    gemm128_dev<0, bf16, 128>(bid % 384, bid / 384, TOK, TOK, 128, 128, 128,
                              WKVT, 128, BKV, KVH, 256, nullptr, nullptr, 0);
  } else {
    // G1: qh = FFB @ WqqT + bqq  (M=16384, K=1024, N=128)
    gemm128_dev<0, bf16, 128>(bid - 768, 0, FFB, FFB, 1024, 1024, 1024,
                              WQQT, 1024, BQQ, QH, 128, nullptr, nullptr, 0);
  }
}

// ---------------------------------------------------------------------------
// gemm256 (R6 schedule — best measured): 256x256 tile, BK=64, 8 waves (2Mx4N),
// wave 128x64, 2x64KB LDS dbuf, distance-2 prefetch, counted vmcnt(8), raw
// s_barrier, setprio around MFMA clusters.
// ---------------------------------------------------------------------------
template <int EPI, typename OutT>
__launch_bounds__(512, 2)
__global__ void gemm256(const bf16* A0, const bf16* A1, int ksplit, int lda0, int lda1,
                        const bf16* __restrict__ BT, int K,
                        const float* __restrict__ bias,
                        OutT* out, int ldo,
                        const bf16* ffp, const bf16* ctxp, int ldfc)
{
  __shared__ uint16_t smA[2][256 * 64];
  __shared__ uint16_t smB[2][256 * 64];
  const int tid = threadIdx.x;
  const int w = tid >> 6;       // wave 0..7
  const int l = tid & 63;
  const int m0 = blockIdx.x * 256;
  const int n0 = blockIdx.y * 256;
  const int wr = w >> 2;        // M-half 0..1
  const int wc = w & 3;         // N-quarter 0..3
  const int lrow = l & 15, lquad = l >> 4;
  const int rb = tid >> 3;      // staging row within 64-row group
  const int cpos = tid & 7;     // staging 16B-chunk position
  const int NT = K >> 6;

  const f32x4 vzero = {0.f, 0.f, 0.f, 0.f};
  f32x4 acc[8][4];
#pragma unroll
  for (int mi = 0; mi < 8; mi++)
#pragma unroll
    for (int ni = 0; ni < 4; ni++) acc[mi][ni] = vzero;

  auto stage = [&](int buf, int tt) {
    const int k0 = tt << 6;
    const bf16* Ab; int la, kc;
    if (k0 < ksplit) { Ab = A0; la = lda0; kc = k0; }
    else             { Ab = A1; la = lda1; kc = k0 - ksplit; }
#pragma unroll
    for (int i = 0; i < 4; i++) {
      const int row = i * 64 + rb;
      const int cg = cpos ^ (row & 7);
      async_ld16(Ab + (size_t)(m0 + row) * la + kc + cg * 8,
                 &smA[buf][(i * 64 + w * 8) * 64]);
    }
#pragma unroll
    for (int i = 0; i < 4; i++) {
      const int row = i * 64 + rb;
      const int cg = cpos ^ (row & 7);
      async_ld16(BT + (size_t)(n0 + row) * K + k0 + cg * 8,
                 &smB[buf][(i * 64 + w * 8) * 64]);
    }
  };

  int cur = 0;

  auto readfrags = [&](int kk, bf16x8 (&af)[8], bf16x8 (&bfr)[4]) {
    const int cc = kk * 4 + lquad;
#pragma unroll
    for (int mi = 0; mi < 8; mi++) {
      int r = wr * 128 + mi * 16 + lrow;
      af[mi] = *(const bf16x8*)&smA[cur][r * 64 + (((cc) ^ (r & 7)) << 3)];
    }
#pragma unroll
    for (int ni = 0; ni < 4; ni++) {
      int r = wc * 64 + ni * 16 + lrow;
      bfr[ni] = *(const bf16x8*)&smB[cur][r * 64 + (((cc) ^ (r & 7)) << 3)];
    }
  };
  auto domfma = [&](bf16x8 (&af)[8], bf16x8 (&bfr)[4]) {
#pragma unroll
    for (int mi = 0; mi < 8; mi++)
#pragma unroll
      for (int ni = 0; ni < 4; ni++)
        acc[mi][ni] =
            __builtin_amdgcn_mfma_f32_16x16x32_bf16(af[mi], bfr[ni], acc[mi][ni], 0, 0, 0);
  };

  // prologue: stage tiles 0,1; wait tile 0 (8 oldest loads), sync.
  stage(0, 0);
  stage(1, 1);
  asm volatile("s_waitcnt vmcnt(8)" ::: "memory");
  __builtin_amdgcn_s_barrier();
  __builtin_amdgcn_sched_barrier(0);

  for (int t = 0; t < NT; ++t) {
    bf16x8 af[8], bfr[4];
    readfrags(0, af, bfr);
    __builtin_amdgcn_s_setprio(1);
    domfma(af, bfr);
    __builtin_amdgcn_s_setprio(0);
    readfrags(1, af, bfr);
    asm volatile("s_waitcnt lgkmcnt(0)" ::: "memory");  // all buf[cur] reads done
    __builtin_amdgcn_s_barrier();                       // ...for every wave
    __builtin_amdgcn_sched_barrier(0);
    if (t + 2 < NT) stage(cur, t + 2);                  // safe: buf[cur] free
    __builtin_amdgcn_s_setprio(1);
    domfma(af, bfr);
    __builtin_amdgcn_s_setprio(0);
    if (t + 2 < NT) {
      asm volatile("s_waitcnt vmcnt(8)" ::: "memory");  // tile t+1 landed
    } else {
      asm volatile("s_waitcnt vmcnt(0)" ::: "memory");  // tail: drain
    }
    __builtin_amdgcn_s_barrier();
    __builtin_amdgcn_sched_barrier(0);
    cur ^= 1;
  }

  // epilogue: C/D layout col=lane&15, row=(lane>>4)*4+reg
#pragma unroll
  for (int mi = 0; mi < 8; mi++) {
#pragma unroll
    for (int ni = 0; ni < 4; ni++) {
#pragma unroll
      for (int r = 0; r < 4; r++) {
        int row = m0 + wr * 128 + mi * 16 + lquad * 4 + r;
        int col = n0 + wc * 64 + ni * 16 + lrow;
        float v = acc[mi][ni][r] + (bias ? bias[col] : 0.f);
        if (EPI == 1) v = gelu_f(v);
        if (EPI == 2) {
          float gate = sigmoid_f(v);
          size_t fo = (size_t)row * ldfc + col;
          v = b2f(ffp[fo]) + gate * b2f(ctxp[fo]);
        }
        if constexpr (__is_same(OutT, float))
          out[(size_t)row * ldo + col] = v;
        else
          out[(size_t)row * ldo + col] = f2b(v);
      }
    }
  }
}

// ---------------------------------------------------------------------------
// emb28 with 256-thread blocks (writes guarded to t<128; syncs unconditional).
// ---------------------------------------------------------------------------
__device__ __forceinline__ void emb28_256(const float* __restrict__ logits,
                                          const float* __restrict__ g,
                                          const float* __restrict__ bb,
                                          const float* __restrict__ W,
                                          const float* __restrict__ wb,
                                          bf16* __restrict__ out, int t,
                                          float* sv, float* sp)
{
  if (t < 28) sv[t] = logits[t];
  __syncthreads();
  float mx = sv[0];
#pragma unroll
  for (int e = 1; e < 28; e++) mx = fmaxf(mx, sv[e]);
  if (t < 28) sp[t] = __expf(sv[t] - mx);
  __syncthreads();
  float sum = 0.f;
#pragma unroll
  for (int e = 0; e < 28; e++) sum += sp[e];
  float inv = 1.f / sum;
  float sp2 = 0.f;
#pragma unroll
  for (int e = 0; e < 28; e++) { float p = sp[e] * inv; sp2 += p * p; }
  const float mean = 1.f / 28.f;
  float var = sp2 * (1.f / 28.f) - mean * mean;
  float rstd = rsqrtf(var + 1e-5f);
  __syncthreads();
  if (t < 28) sp[t] = (sp[t] * inv - mean) * rstd * g[t] + bb[t];
  __syncthreads();
  if (t < 128) {
    float acc = wb[t];
#pragma unroll
    for (int e = 0; e < 28; e++) acc += sp[e] * W[e * 128 + t];
    out[t] = f2b(gelu_f(acc));
  }
  __syncthreads();
}

// ---------------------------------------------------------------------------
// Preamble: one launch, grid-partitioned.
//  [0, 16384)           : ffb convert (row b) + tokens (row b), 256 thr
//  [16384, 16384+3600)  : weight transposes (32x32 tiles via LDS 32x33)
//  [19984, 20694)       : prep_small scatter (WKVT/BKV/BQQ/BOC/WQINB/WOB)
// ---------------------------------------------------------------------------
__global__ void preamble(
    const float* __restrict__ ff, bf16* __restrict__ FFB,
    const float* __restrict__ exl, const float* __restrict__ iml, const float* __restrict__ affv,
    const float* __restrict__ geg, const float* __restrict__ geb,
    const float* __restrict__ Wex, const float* __restrict__ bex,
    const float* __restrict__ gig, const float* __restrict__ gib,
    const float* __restrict__ Wim, const float* __restrict__ bim,
    const float* __restrict__ gag, const float* __restrict__ gab,
    const float* __restrict__ Waf, const float* __restrict__ baf,
    bf16* __restrict__ TOK,
    const float* __restrict__ Wq, const float* __restrict__ Wc,
    const float* __restrict__ Ws, const float* __restrict__ Wg1,
    const float* __restrict__ Wg2,
    bf16* WQT, bf16* WCT, bf16* WST, bf16* WG1T, bf16* WG2T,
    const float* __restrict__ Wk, const float* __restrict__ bk,
    const float* __restrict__ Wv, const float* __restrict__ bv,
    const float* __restrict__ Wq_in, const float* __restrict__ bq_in,
    const float* __restrict__ bq, const float* __restrict__ Wo,
    const float* __restrict__ bo, const float* __restrict__ bc,
    bf16* WKVT, float* BKV, float* BQQ, float* BOC, bf16* WQINB, bf16* WOB)
{
  __shared__ float tile[32][33];
  __shared__ float sv[28], sp[28];
  int bid = blockIdx.x;
  const int t = threadIdx.x;

  if (bid < 16384) {
    // --- ffb convert: row bid (1024 floats, 4/thread) ---
    size_t i = (size_t)bid * 1024 + (size_t)t * 4;
    float4 v = *reinterpret_cast<const float4*>(ff + i);
    ushort4 o;
    o.x = __builtin_bit_cast(unsigned short, f2b(v.x));
    o.y = __builtin_bit_cast(unsigned short, f2b(v.y));
    o.z = __builtin_bit_cast(unsigned short, f2b(v.z));
    o.w = __builtin_bit_cast(unsigned short, f2b(v.w));
    *reinterpret_cast<ushort4*>(FFB + i) = o;
    // --- tokens: row bid ---
    bf16* trow = TOK + (size_t)bid * 384;
    emb28_256(exl + (size_t)bid * 28, geg, geb, Wex, bex, trow, t, sv, sp);
    emb28_256(iml + (size_t)bid * 28, gig, gib, Wim, bim, trow + 128, t, sv, sp);
    if (t < 128) {
      float a0 = affv[(size_t)bid * 2 + 0];
      float a1 = affv[(size_t)bid * 2 + 1];
      float m = 0.5f * (a0 + a1);
      float d0 = a0 - m, d1 = a1 - m;
      float var = 0.5f * (d0 * d0 + d1 * d1);
      float rstd = rsqrtf(var + 1e-5f);
      float l0 = d0 * rstd * gag[0] + gab[0];
      float l1 = d1 * rstd * gag[1] + gab[1];
      float acc = baf[t] + l0 * Waf[t] + l1 * Waf[128 + t];
      trow[256 + t] = f2b(gelu_f(acc));
    }
    return;
  }
  bid -= 16384;
  if (bid < 3600) {
    // --- transposes: out[c][r] = (bf16)in[r][c] ---
    const float* in; bf16* outp; int R, C, bx, by;
    if (bid < 16)                 { in = Wq;  outp = WQT;  R = 128;  C = 128;  bx = bid & 3;  by = bid >> 2; }
    else if ((bid -= 16) < 128)   { in = Wc;  outp = WCT;  R = 128;  C = 1024; bx = bid & 31; by = bid >> 5; }
    else if ((bid -= 128) < 384)  { in = Ws;  outp = WST;  R = 384;  C = 1024; bx = bid & 31; by = bid >> 5; }
    else if ((bid -= 384) < 2048) { in = Wg1; outp = WG1T; R = 2048; C = 1024; bx = bid & 31; by = bid >> 5; }
    else { bid -= 2048;             in = Wg2; outp = WG2T; R = 1024; C = 1024; bx = bid & 31; by = bid >> 5; }
    const int tx = t & 31, ty = t >> 5;  // ty in [0,8)
    const int c0 = bx * 32, r0 = by * 32;
#pragma unroll
    for (int i = 0; i < 4; i++) {
      int r = ty + i * 8;
      tile[r][tx] = in[(size_t)(r0 + r) * C + c0 + tx];
    }
    __syncthreads();
#pragma unroll
    for (int i = 0; i < 4; i++) {
      int c = ty + i * 8;
      outp[(size_t)(c0 + c) * R + r0 + tx] = f2b(tile[tx][c]);
    }
    return;
  }
  bid -= 3600;
  // --- prep_small scatter ---
  int idx = bid * 256 + t;
  if (idx < 32768) {
    int n = idx >> 7, k = idx & 127;
    WKVT[idx] = f2b((n < 128) ? Wk[k * 128 + n] : Wv[k * 128 + (n - 128)]);
    return;
  }
  idx -= 32768;
  if (idx < 256) { BKV[idx] = (idx < 128) ? bk[idx] : bv[idx - 128]; return; }
  idx -= 256;
  if (idx < 128) {
    float s = bq[idx];
    for (int u = 0; u < 128; u++) s += bq_in[u] * Wq[u * 128 + idx];
    BQQ[idx] = s;
    return;
  }
  idx -= 128;
  if (idx < 1024) {
    float s = bc[idx];
    for (int u = 0; u < 128; u++) s += bo[u] * Wc[u * 1024 + idx];
    BOC[idx] = s;
    return;
  }
  idx -= 1024;
  if (idx < 131072) { WQINB[idx] = f2b(Wq_in[idx]); return; }
  idx -= 131072;
  if (idx < 16384) { WOB[idx] = f2b(Wo[idx]); return; }
}

// ---------------------------------------------------------------------------
__global__ void attn_kernel(const bf16* __restrict__ qh, const bf16* __restrict__ kvh,
                            bf16* __restrict__ apre, float* __restrict__ attw)
{
  const int b = blockIdx.x, t = threadIdx.x;  // 128 threads
  float q = b2f(qh[(size_t)b * 128 + t]);
  const bf16* kv = kvh + (size_t)b * 3 * 256;
  float s[3], v[3];
#pragma unroll
  for (int i = 0; i < 3; i++) {
    float k = b2f(kv[i * 256 + t]);
    v[i] = b2f(kv[i * 256 + 128 + t]);
    float r = q * k;
#pragma unroll
    for (int off = 16; off > 0; off >>= 1) r += __shfl_down(r, off, 32);
    r = __shfl(r, 0, 32);
    s[i] = r * 0.17677669529663687f;  // 1/sqrt(32)
  }
  float mx = fmaxf(s[0], fmaxf(s[1], s[2]));
  float e0 = __expf(s[0] - mx), e1 = __expf(s[1] - mx), e2 = __expf(s[2] - mx);
  float inv = 1.f / (e0 + e1 + e2);
  float w0 = e0 * inv, w1 = e1 * inv, w2 = e2 * inv;
  apre[(size_t)b * 128 + t] = f2b(w0 * v[0] + w1 * v[1] + w2 * v[2]);
  __shared__ float aw[4][3];
  if ((t & 31) == 0) { int h = t >> 5; aw[h][0] = w0; aw[h][1] = w1; aw[h][2] = w2; }
  __syncthreads();
  if (t < 3)
    attw[(size_t)b * 3 + t] = 0.25f * (aw[0][t] + aw[1][t] + aw[2][t] + aw[3][t]);
}

// ---------------------------------------------------------------------------
__global__ void ln_out_kernel(const bf16* __restrict__ x, const float* __restrict__ g,
                              const float* __restrict__ bb, float* __restrict__ out)
{
  const int row = blockIdx.x, t = threadIdx.x;
  const bf16* xr = x + (size_t)row * 1024;
  ushort4 u = *reinterpret_cast<const ushort4*>(xr + t * 4);
  float v0 = __uint_as_float((uint32_t)u.x << 16);
  float v1 = __uint_as_float((uint32_t)u.y << 16);
  float v2 = __uint_as_float((uint32_t)u.z << 16);
  float v3 = __uint_as_float((uint32_t)u.w << 16);
  float s = v0 + v1 + v2 + v3;
  float s2 = v0 * v0 + v1 * v1 + v2 * v2 + v3 * v3;
#pragma unroll
  for (int off = 32; off > 0; off >>= 1) {
    s += __shfl_down(s, off, 64);
    s2 += __shfl_down(s2, off, 64);
  }
  __shared__ float ls[4], ls2[4];
  const int w = t >> 6;
  if ((t & 63) == 0) { ls[w] = s; ls2[w] = s2; }
  __syncthreads();
  float S = ls[0] + ls[1] + ls[2] + ls[3];
  float S2 = ls2[0] + ls2[1] + ls2[2] + ls2[3];
  float mean = S * (1.f / 1024.f);
  float var = S2 * (1.f / 1024.f) - mean * mean;
  float rstd = rsqrtf(var + 1e-5f);
  const int c = t * 4;
  float4 o;
  o.x = (v0 - mean) * rstd * g[c + 0] + bb[c + 0];
  o.y = (v1 - mean) * rstd * g[c + 1] + bb[c + 1];
  o.z = (v2 - mean) * rstd * g[c + 2] + bb[c + 2];
  o.w = (v3 - mean) * rstd * g[c + 3] + bb[c + 3];
  *reinterpret_cast<float4*>(out + (size_t)row * 1024 + c) = o;
}

// ---------------------------------------------------------------------------
extern "C" void kernel_launch(void* const* d_in, const int* in_sizes, int n_in,
                              void* d_out, int out_size, void* d_ws, size_t ws_size,
                              hipStream_t stream)
{
  const float* ff   = (const float*)d_in[0];
  const float* exl  = (const float*)d_in[1];
  const float* iml  = (const float*)d_in[2];
  const float* affv = (const float*)d_in[3];
  const float* geg = (const float*)d_in[4],  *geb = (const float*)d_in[5];
  const float* Wex = (const float*)d_in[6],  *bex = (const float*)d_in[7];
  const float* gig = (const float*)d_in[8],  *gib = (const float*)d_in[9];
  const float* Wim = (const float*)d_in[10], *bim = (const float*)d_in[11];
  const float* gag = (const float*)d_in[12], *gab = (const float*)d_in[13];
  const float* Waf = (const float*)d_in[14], *baf = (const float*)d_in[15];
  const float* Wq_in = (const float*)d_in[16], *bq_in = (const float*)d_in[17];
  const float* Wq = (const float*)d_in[18], *bq = (const float*)d_in[19];
  const float* Wk = (const float*)d_in[20], *bk = (const float*)d_in[21];
  const float* Wv = (const float*)d_in[22], *bv = (const float*)d_in[23];
  const float* Wo = (const float*)d_in[24], *bo = (const float*)d_in[25];
  const float* Wc = (const float*)d_in[26], *bc = (const float*)d_in[27];
  const float* Ws = (const float*)d_in[28], *bs = (const float*)d_in[29];
  const float* Wg1 = (const float*)d_in[30], *bg1 = (const float*)d_in[31];
  const float* Wg2 = (const float*)d_in[32], *bg2 = (const float*)d_in[33];
  const float* lng = (const float*)d_in[34], *lnb = (const float*)d_in[35];

  // workspace layout (bytes); peak = 62,199,296 (~59.3 MB)
  char* ws = (char*)d_ws;
  bf16*  WKVT = (bf16*)(ws + 0);         //  32768 el bf16
  float* BKV  = (float*)(ws + 65536);    //    256 el f32
  bf16*  WQQT = (bf16*)(ws + 66560);     // 131072 el bf16
  float* BQQ  = (float*)(ws + 328704);   //    128 el f32
  bf16*  WOCT = (bf16*)(ws + 329216);    // 131072 el bf16
  float* BOC  = (float*)(ws + 591360);   //   1024 el f32
  bf16*  WST  = (bf16*)(ws + 595456);    // 393216 el bf16
  bf16*  WG1T = (bf16*)(ws + 1381888);   // 2097152 el bf16
  bf16*  WG2T = (bf16*)(ws + 5576192);   // 1048576 el bf16
  bf16*  FFB  = (bf16*)(ws + 7673344);   // B*1024 (live: preamble..G6)
  bf16*  PRE  = (bf16*)(ws + 7673344);   // B*1024, aliases FFB elem-wise (G6..ln)
  bf16*  TOK  = (bf16*)(ws + 41227776);  // B*384  (live: preamble..G4)
  bf16*  QH   = (bf16*)(ws + 53810688);  // B*128  (live: g12..attn)
  bf16*  APRE = (bf16*)(ws + 58004992);  // B*128  (live: attn..G3)

  // prep temporaries carved from the (not-yet-live) QH slot (4 MB avail):
  bf16* WQT   = (bf16*)(ws + 53810688);            //  16384 el (Wq^T)
  bf16* WOB   = (bf16*)(ws + 53810688 + 32768);    //  16384 el (Wo bf16)
  bf16* WQINB = (bf16*)(ws + 53810688 + 65536);    // 131072 el (Wq_in bf16)
  bf16* WCT   = (bf16*)(ws + 53810688 + 327680);   // 131072 el (Wc^T)

  float* outp = (float*)d_out;
  float* out_refined = outp;             // B*1024 f32; hosts CTX bf16 G3..G6
  float* out_attw    = outp + 16777216;  // B*3 f32
  float* out_summary = outp + 16826368;  // B*1024 f32; hosts KVH bf16 G2..attn, GATEH bf16 G5..G6
  bf16* CTX   = (bf16*)out_refined;
  bf16* KVH   = (bf16*)out_summary;
  bf16* GATEH = (bf16*)out_summary;

  // 1: preamble — ffb + tokens + transposes + prep scatter
  preamble<<<20694, 256, 0, stream>>>(
      ff, FFB, exl, iml, affv, geg, geb, Wex, bex, gig, gib, Wim, bim,
      gag, gab, Waf, baf, TOK,
      Wq, Wc, Ws, Wg1, Wg2, WQT, WCT, WST, WG1T, WG2T,
      Wk, bk, Wv, bv, Wq_in, bq_in, bq, Wo, bo, bc,
      WKVT, BKV, BQQ, BOC, WQINB, WOB);
  // 2: both weight folds
  folds_k<<<16, 256, 0, stream>>>(WQT, WQINB, WQQT, WCT, WOB, WOCT);
  // 3: G2 + G1
  g12_k<<<896, 256, 0, stream>>>(FFB, WQQT, BQQ, QH, TOK, WKVT, BKV, KVH);
  // 4: attention
  attn_kernel<<<16384, 128, 0, stream>>>(QH, KVH, APRE, out_attw);
  // 5: G3 ctx = APRE @ WocT + boc  (M=16384, K=128, N=1024)
  gemm128_k<0, bf16, 128><<<dim3(128, 8), 256, 0, stream>>>(APRE, APRE, 128, 128, 128, WOCT, 128,
                                                            BOC, CTX, 1024, nullptr, nullptr, 0);
  // 6: G5 gate_h = gelu([FFB|CTX] @ Wg1T + bg1)  (K=2048)
  gemm256<1, bf16><<<dim3(64, 4), 512, 0, stream>>>(FFB, CTX, 1024, 1024, 1024, WG1T, 2048,
                                                    bg1, GATEH, 1024, nullptr, nullptr, 0);
  // 7: G6 pre = FFB + sigmoid(gate_h @ Wg2T + bg2) * ctx
  gemm256<2, bf16><<<dim3(64, 4), 512, 0, stream>>>(GATEH, GATEH, 1024, 1024, 1024, WG2T, 1024,
                                                    bg2, PRE, 1024, FFB, CTX, 1024);
  // 8: G4 summary = gelu(TOK @ WsT + bs)  (K=384)
  gemm256<1, float><<<dim3(64, 4), 512, 0, stream>>>(TOK, TOK, 384, 384, 384, WST, 384,
                                                     bs, out_summary, 1024, nullptr, nullptr, 0);
  // 9: final LN
  ln_out_kernel<<<16384, 256, 0, stream>>>(PRE, lng, lnb, out_refined);
}